// Round 15
// baseline (221.427 us; speedup 1.0000x reference)
//
#include <hip/hip_runtime.h>
#include <hip/hip_bf16.h>
#include <cstdint>
#include <math.h>

#define B 2
#define S 3072
#define D 512
#define H 8
#define HD 64
#define DFF 2048
#define R 768
#define SC (S - R)
#define EPS 1e-5f
#define QSCALE 0.1803368801111137f   // log2(e)/sqrt(64) folded into Q
#define NKH 4                        // split-K factor

typedef __attribute__((ext_vector_type(8))) short s8v;   // 8 x bf16 (4 VGPR)
typedef __attribute__((ext_vector_type(4))) short s4v;   // 4 x bf16 (2 VGPR)
typedef __attribute__((ext_vector_type(4))) float f4v;   // mfma accumulator

__device__ inline short f2bf(float x) {
    __hip_bfloat16 h = __float2bfloat16(x);
    return __builtin_bit_cast(short, h);
}
__device__ inline float bf2f(short s) {
    unsigned int u = (unsigned int)(unsigned short)s << 16;
    return __builtin_bit_cast(float, u);
}
__device__ inline unsigned int pack2bf(float a, float b) {
    return (unsigned int)(unsigned short)f2bf(a) |
           ((unsigned int)(unsigned short)f2bf(b) << 16);
}

// K=16 bf16 MFMA (PV sub-tiles): builtin if present, else raw asm.
__device__ __forceinline__ f4v mfma16(s4v a, s4v b, f4v c) {
#if __has_builtin(__builtin_amdgcn_mfma_f32_16x16x16bf16_1k)
    return __builtin_amdgcn_mfma_f32_16x16x16bf16_1k(a, b, c, 0, 0, 0);
#else
    asm("v_mfma_f32_16x16x16_bf16 %0, %1, %2, %0" : "+v"(c) : "v"(a), "v"(b));
    return c;
#endif
}

// global -> LDS direct 16B load
__device__ __forceinline__ void gload16(const short* g, short* l) {
    auto l3 = reinterpret_cast<__attribute__((address_space(3))) short*>(
        reinterpret_cast<uintptr_t>(l));
    auto g1 = reinterpret_cast<const __attribute__((address_space(1))) short*>(
        reinterpret_cast<uintptr_t>(g));
    __builtin_amdgcn_global_load_lds(g1, l3, 16, 0, 0);
}

// ---------------------------------------------------------------------------
// Fused fp32 -> bf16 conversion: src + all 4 weight matrices, one launch.
// ---------------------------------------------------------------------------
__global__ __launch_bounds__(256) void cvt_all(
    const float* __restrict__ src, const float* __restrict__ w_in,
    const float* __restrict__ w_out, const float* __restrict__ w_1,
    const float* __restrict__ w_2,
    short* __restrict__ o_src, short* __restrict__ o_in,
    short* __restrict__ o_out, short* __restrict__ o_1,
    short* __restrict__ o_2)
{
    int i = (blockIdx.x * 256 + threadIdx.x) * 4;
    const int nS = B * S * D;
    const int n0 = nS + 3 * D * D, n1 = n0 + D * D, n2 = n1 + DFF * D;
    const int n3 = n2 + D * DFF;
    if (i >= n3) return;
    const float* sp; short* dp; int off;
    if (i < nS)      { sp = src;   dp = o_src; off = i; }
    else if (i < n0) { sp = w_in;  dp = o_in;  off = i - nS; }
    else if (i < n1) { sp = w_out; dp = o_out; off = i - n0; }
    else if (i < n2) { sp = w_1;   dp = o_1;   off = i - n1; }
    else             { sp = w_2;   dp = o_2;   off = i - n2; }
    float4 v = *(const float4*)(sp + off);
    short4 o = { f2bf(v.x), f2bf(v.y), f2bf(v.z), f2bf(v.w) };
    *(short4*)(dp + off) = o;
}

// ---------------------------------------------------------------------------
// 128x128 bf16 MFMA GEMM (m97 structure) — verified.  Used for FFN1 only.
// ---------------------------------------------------------------------------
template<int MODE, int RELU, int OUTBF>
__global__ __launch_bounds__(256) void gemm128(
    const short* __restrict__ A, const short* __restrict__ W,
    const float* __restrict__ bias, void* __restrict__ C0v,
    void* __restrict__ C1v, int M, int N, int K,
    const int* __restrict__ gather_idx)
{
    __shared__ short Al[128 * 32];
    __shared__ short Bl[128 * 32];
    const int t = threadIdx.x;
    const int bm = blockIdx.y * 128, bn = blockIdx.x * 128;
    const int lane = t & 63, w = t >> 6;
    const int wm = (w >> 1) * 64, wn = (w & 1) * 64;
    const int lr = lane & 15, lk = lane >> 4;

    const int q1 = t, q2 = t + 256;
    const int r1 = q1 >> 2, c1 = (q1 & 3) ^ (r1 & 3);
    const int r2 = q2 >> 2, c2 = (q2 & 3) ^ (r2 & 3);
    long ga1 = (long)(bm + r1) * K + c1 * 8;
    long ga2 = (long)(bm + r2) * K + c2 * 8;
    const long gb1 = (long)(bn + r1) * K + c1 * 8;
    const long gb2 = (long)(bn + r2) * K + c2 * 8;

    f4v acc[4][4] = {};

    for (int k0 = 0; k0 < K; k0 += 32) {
        __syncthreads();
        gload16(A + ga1 + k0, Al + q1 * 8);
        gload16(A + ga2 + k0, Al + q2 * 8);
        gload16(W + gb1 + k0, Bl + q1 * 8);
        gload16(W + gb2 + k0, Bl + q2 * 8);
        __syncthreads();

        s8v af[4], bf[4];
#pragma unroll
        for (int mi = 0; mi < 4; mi++) {
            int ra = wm + mi * 16 + lr;
            af[mi] = *(const s8v*)&Al[ra * 32 + ((lk ^ (ra & 3)) * 8)];
        }
#pragma unroll
        for (int ni = 0; ni < 4; ni++) {
            int rb = wn + ni * 16 + lr;
            bf[ni] = *(const s8v*)&Bl[rb * 32 + ((lk ^ (rb & 3)) * 8)];
        }
#pragma unroll
        for (int mi = 0; mi < 4; mi++)
#pragma unroll
            for (int ni = 0; ni < 4; ni++)
                acc[mi][ni] = __builtin_amdgcn_mfma_f32_16x16x32_bf16(
                    af[mi], bf[ni], acc[mi][ni], 0, 0, 0);
    }

#pragma unroll
    for (int mi = 0; mi < 4; mi++) {
#pragma unroll
        for (int ni = 0; ni < 4; ni++) {
#pragma unroll
            for (int i = 0; i < 4; i++) {
                int m = bm + wm + mi * 16 + lk * 4 + i;
                int n = bn + wn + ni * 16 + lr;
                float v = acc[mi][ni][i] + bias[n];
                if (RELU) v = fmaxf(v, 0.f);
                if (OUTBF) ((short*)C0v)[(long)m * N + n] = f2bf(v);
                else       ((float*)C0v)[(long)m * N + n] = v;
            }
        }
    }
}

// ---------------------------------------------------------------------------
// 64x64 bf16 MFMA GEMM body, BK=128: halves barrier count vs BK=64.
// Swizzle: LDS chunk (row, slot) holds global k-chunk slot^(row&15);
// read slot' = (ks*4+lk) ^ (row&15).  16 distinct slots per 16-lane group
// -> 2 lanes/bank = free.  Same involution on source and read (rule #21).
// ---------------------------------------------------------------------------
template<int MODE, int RELU, int OUTBF>
__device__ __forceinline__ void gemm64_body(
    const short* __restrict__ A, const short* __restrict__ W,
    const float* __restrict__ bias, void* __restrict__ C0v,
    void* __restrict__ C1v, int M, int N, int K,
    const int* __restrict__ gather_idx, int bm, int bn,
    short* Al, short* Bl)
{
    const int t = threadIdx.x;
    const int lane = t & 63, w = t >> 6;
    const int wm = (w >> 1) * 32, wn = (w & 1) * 32;
    const int lr = lane & 15, lk = lane >> 4;

    // staging: 1024 chunks (16B) per matrix per K-tile; 4 chunks/thread.
    long gav[4], gbv[4];
#pragma unroll
    for (int c = 0; c < 4; c++) {
        int cq = t + c * 256;
        int row = cq >> 4, slot = cq & 15;
        int gcol = (slot ^ (row & 15)) * 8;
        if (MODE == 2) {
            int m1 = bm + row; int b1 = m1 >= R; int i1 = m1 - b1 * R;
            gav[c] = ((long)b1 * S + gather_idx[i1]) * K + gcol;
        } else {
            gav[c] = (long)(bm + row) * K + gcol;
        }
        gbv[c] = (long)(bn + row) * K + gcol;
    }

    f4v acc[2][2] = {};

    for (int k0 = 0; k0 < K; k0 += 128) {
        __syncthreads();
#pragma unroll
        for (int c = 0; c < 4; c++) {
            gload16(A + gav[c] + k0, Al + (t + c * 256) * 8);
            gload16(W + gbv[c] + k0, Bl + (t + c * 256) * 8);
        }
        __syncthreads();

#pragma unroll
        for (int ks = 0; ks < 4; ks++) {
            s8v af[2], bf[2];
#pragma unroll
            for (int mi = 0; mi < 2; mi++) {
                int ra = wm + mi * 16 + lr;
                af[mi] = *(const s8v*)&Al[ra * 128 + (((ks * 4 + lk) ^ (ra & 15)) * 8)];
            }
#pragma unroll
            for (int ni = 0; ni < 2; ni++) {
                int rb = wn + ni * 16 + lr;
                bf[ni] = *(const s8v*)&Bl[rb * 128 + (((ks * 4 + lk) ^ (rb & 15)) * 8)];
            }
#pragma unroll
            for (int mi = 0; mi < 2; mi++)
#pragma unroll
                for (int ni = 0; ni < 2; ni++)
                    acc[mi][ni] = __builtin_amdgcn_mfma_f32_16x16x32_bf16(
                        af[mi], bf[ni], acc[mi][ni], 0, 0, 0);
        }
    }

#pragma unroll
    for (int mi = 0; mi < 2; mi++) {
#pragma unroll
        for (int ni = 0; ni < 2; ni++) {
#pragma unroll
            for (int i = 0; i < 4; i++) {
                int m = bm + wm + mi * 16 + lk * 4 + i;
                int n = bn + wn + ni * 16 + lr;
                float v = acc[mi][ni][i] + bias[n];
                if (RELU) v = fmaxf(v, 0.f);
                if (MODE == 0) {
                    if (OUTBF) ((short*)C0v)[(long)m * N + n] = f2bf(v);
                    else       ((float*)C0v)[(long)m * N + n] = v;
                } else if (MODE == 1) {     // Q scatter (pre-scaled) -> bf16
                    int b = m >= S; int s = m - b * S;
                    int h = n >> 6, hd = n & 63;
                    ((short*)C0v)[(((long)(b * H + h)) * S + s) * HD + hd] =
                        f2bf(v * QSCALE);
                } else {                    // K row-major / V transposed
                    int b = m >= R; int i2 = m - b * R;
                    int s = gather_idx[i2];
                    int c = n;
                    if (c < D) {
                        int h = c >> 6, hd = c & 63;
                        ((short*)C0v)[(((long)(b * H + h)) * S + s) * HD + hd] = f2bf(v);
                    } else {
                        c -= D;
                        int h = c >> 6, hd = c & 63;
                        ((short*)C1v)[(((long)(b * H + h)) * HD + hd) * S + s] = f2bf(v);
                    }
                }
            }
        }
    }
}

// plain gemm64 wrapper (out-proj, FFN2)
template<int MODE, int RELU, int OUTBF>
__global__ __launch_bounds__(256) void gemm64(
    const short* __restrict__ A, const short* __restrict__ W,
    const float* __restrict__ bias, void* __restrict__ C0v,
    void* __restrict__ C1v, int M, int N, int K,
    const int* __restrict__ gather_idx)
{
    __shared__ short Al[64 * 128];
    __shared__ short Bl[64 * 128];
    gemm64_body<MODE, RELU, OUTBF>(A, W, bias, C0v, C1v, M, N, K, gather_idx,
                                   blockIdx.y * 64, blockIdx.x * 64, Al, Bl);
}

// fused Q-proj + KV-proj: blocks [0,768) do Q tiles, [768,1152) do KV tiles.
__global__ __launch_bounds__(256) void qkv_proj(
    const short* __restrict__ SRCb, const short* __restrict__ WIb,
    const float* __restrict__ in_b, short* __restrict__ Qb,
    short* __restrict__ KF, short* __restrict__ VT,
    const int* __restrict__ rec_idx)
{
    __shared__ short Al[64 * 128];
    __shared__ short Bl[64 * 128];
    int g = blockIdx.x;
    if (g < (B * S / 64) * (D / 64)) {          // 96*8 = 768 Q tiles
        int bn = (g & 7) * 64, bm = (g >> 3) * 64;
        gemm64_body<1, 0, 0>(SRCb, WIb, in_b, Qb, nullptr,
                             B * S, D, D, rec_idx, bm, bn, Al, Bl);
    } else {                                    // 24*16 = 384 KV tiles
        int gg = g - 768;
        int bn = (gg & 15) * 64, bm = (gg >> 4) * 64;
        gemm64_body<2, 0, 0>(SRCb, WIb + D * D, in_b + D, KF, VT,
                             B * R, 2 * D, D, rec_idx, bm, bn, Al, Bl);
    }
}

// ---------------------------------------------------------------------------
// Fused cached-K + cached-V^T scatter (one launch).
// ---------------------------------------------------------------------------
#define NKBLK ((H * SC * HD) / 256)             // 4608
__global__ __launch_bounds__(256) void scatter_kv(
    const float* __restrict__ kc, const float* __restrict__ vc,
    const int* __restrict__ cidx, short* __restrict__ kf,
    short* __restrict__ vt)
{
    int blk = blockIdx.x;
    if (blk < NKBLK) {
        long e = (long)blk * 256 + threadIdx.x;
        int hd = e & 63;
        long tmp = e >> 6;
        int j = (int)(tmp % SC);
        int h = (int)(tmp / SC);
        int s = cidx[j];
        short v = f2bf(kc[e]);
        kf[(((long)(0 * H + h)) * S + s) * HD + hd] = v;
        kf[(((long)(1 * H + h)) * S + s) * HD + hd] = v;
    } else {
        int bb = blk - NKBLK;                   // 0 .. (SC/64)*H-1 = 287
        const int h = bb / (SC / 64);
        const int jblk = bb % (SC / 64);
        const int hd = threadIdx.x & 63, jg = threadIdx.x >> 6;
        const int j0 = jblk * 64 + jg * 16;
#pragma unroll 4
        for (int jj = 0; jj < 16; jj++) {
            int j = j0 + jj;
            int s = cidx[j];
            short v = f2bf(vc[((long)h * SC + j) * HD + hd]);
            vt[(((long)(0 * H + h)) * HD + hd) * S + s] = v;
            vt[(((long)(1 * H + h)) * HD + hd) * S + s] = v;
        }
    }
}

// ---------------------------------------------------------------------------
// MFMA flash attention v4 (verified R12/R13) — bf16 partial-O output.
// ---------------------------------------------------------------------------
__global__ __launch_bounds__(256) void attn_mfma(
    const short* __restrict__ Qb, const short* __restrict__ KF,
    const short* __restrict__ VT, short* __restrict__ Opart,
    float* __restrict__ ML)
{
    __shared__ short Ks[64 * 64];
    __shared__ short Vt[64 * 64];
    const int t = threadIdx.x;
    const int lane = t & 63, w = t >> 6;
    const int lr = lane & 15, lk = lane >> 4;
    const int nq = S / 64;
    const int qt = blockIdx.x % nq;
    const int bh = blockIdx.x / nq;
    const int kh = blockIdx.y;
    const long base = (long)bh * S;

    const int qrow = qt * 64 + w * 16 + lr;
    const s8v qf0 = *(const s8v*)&Qb[(base + qrow) * HD + lk * 8];
    const s8v qf1 = *(const s8v*)&Qb[(base + qrow) * HD + 32 + lk * 8];

    const int cq1 = t, cq2 = t + 256;
    const int sr1 = cq1 >> 3, sc1 = (cq1 & 7) ^ (sr1 & 7);
    const int sr2 = cq2 >> 3, sc2 = (cq2 & 7) ^ (sr2 & 7);
    const long kb1 = (base + sr1) * HD + sc1 * 8;
    const long kb2 = (base + sr2) * HD + sc2 * 8;
    const long vb1 = ((long)bh * HD + sr1) * S + sc1 * 8;
    const long vb2 = ((long)bh * HD + sr2) * S + sc2 * 8;

    f4v od[4] = {};
    f4v lsum = {};
    const s4v ones = { 0x3F80, 0x3F80, 0x3F80, 0x3F80 };  // bf16 1.0 x4

    const int kbeg = kh * (S / NKH), kend = kbeg + S / NKH;
    for (int k0 = kbeg; k0 < kend; k0 += 64) {
        __syncthreads();
        gload16(KF + kb1 + (long)k0 * HD, Ks + cq1 * 8);
        gload16(KF + kb2 + (long)k0 * HD, Ks + cq2 * 8);
        gload16(VT + vb1 + k0, Vt + cq1 * 8);
        gload16(VT + vb2 + k0, Vt + cq2 * 8);
        __syncthreads();

        f4v sc[4];
#pragma unroll
        for (int st = 0; st < 4; st++) {
            const int row = st * 16 + lr;
            s8v kf0 = *(const s8v*)&Ks[row * 64 + ((lk ^ (lr & 7)) * 8)];
            s8v kf1 = *(const s8v*)&Ks[row * 64 + (((4 + lk) ^ (lr & 7)) * 8)];
            f4v a = {};
            a = __builtin_amdgcn_mfma_f32_16x16x32_bf16(kf0, qf0, a, 0, 0, 0);
            a = __builtin_amdgcn_mfma_f32_16x16x32_bf16(kf1, qf1, a, 0, 0, 0);
            sc[st] = a;
        }

        s4v pa[4];
#pragma unroll
        for (int st = 0; st < 4; st++) {
            float e0 = exp2f(sc[st][0]), e1 = exp2f(sc[st][1]);
            float e2 = exp2f(sc[st][2]), e3 = exp2f(sc[st][3]);
            int2 pw = { (int)pack2bf(e0, e1), (int)pack2bf(e2, e3) };
            pa[st] = __builtin_bit_cast(s4v, pw);
            lsum = mfma16(pa[st], ones, lsum);   // row-sum on MFMA pipe
        }

#pragma unroll
        for (int dst = 0; dst < 4; dst++) {
            const int d = dst * 16 + lr;
#pragma unroll
            for (int st = 0; st < 4; st++) {
                int cc = 2 * st + (lk >> 1);
                s4v vf = *(const s4v*)&Vt[d * 64 + ((cc ^ (lr & 7)) * 8) + (lk & 1) * 4];
                od[dst] = mfma16(pa[st], vf, od[dst]);
            }
        }
    }

    const long pb = ((long)(kh * 16 + bh)) * S;
    if (lr == 0) {
#pragma unroll
        for (int i = 0; i < 4; i++) {
            int q = qt * 64 + w * 16 + lk * 4 + i;
            ML[pb + q] = lsum[i];
        }
    }
#pragma unroll
    for (int dst = 0; dst < 4; dst++)
#pragma unroll
        for (int i = 0; i < 4; i++) {
            int q = qt * 64 + w * 16 + lk * 4 + i;
            int d = dst * 16 + lr;
            Opart[(pb + q) * HD + d] = f2bf(od[dst][i]);
        }
}

// ---------------------------------------------------------------------------
// Combine NKH key-slice bf16 partials: O = sum O_i / sum l_i -> bf16 ctx.
// ---------------------------------------------------------------------------
__global__ __launch_bounds__(256) void attn_combine(
    const short* __restrict__ Opart, const float* __restrict__ ML,
    short* __restrict__ ctxb)
{
    long idx = (long)blockIdx.x * 256 + threadIdx.x;
    long f = idx * 4;
    int d = (int)(f & 63);
    long x = f >> 6;
    int bh = (int)(x / S);
    int q = (int)(x - (long)bh * S);
    float l = 0.f;
    float4 o = {0.f, 0.f, 0.f, 0.f};
#pragma unroll
    for (int kh = 0; kh < NKH; kh++) {
        long xx = x + (long)kh * 16 * S;
        l += ML[xx];
        short4 p = *(const short4*)&Opart[xx * HD + d];
        o.x += bf2f(p.x); o.y += bf2f(p.y);
        o.z += bf2f(p.z); o.w += bf2f(p.w);
    }
    float inv = 1.f / l;
    int b = bh >> 3, h = bh & 7;
    short4 r;
    r.x = f2bf(o.x * inv);
    r.y = f2bf(o.y * inv);
    r.z = f2bf(o.z * inv);
    r.w = f2bf(o.w * inv);
    *(short4*)&ctxb[((long)(b * S + q)) * D + h * HD + d] = r;
}

// ---------------------------------------------------------------------------
template<int WB>
__global__ __launch_bounds__(256) void ln_kernel(
    const float* __restrict__ a, const float* __restrict__ r,
    const float* __restrict__ g, const float* __restrict__ be,
    float* __restrict__ out, short* __restrict__ outb)
{
    const long row = blockIdx.x;
    const int t = threadIdx.x;
    const float* pa = a + row * D;
    const float* pr = r + row * D;
    float v0 = pa[t] + pr[t];
    float v1 = pa[t + 256] + pr[t + 256];
    float s1 = v0 + v1, s2 = v0 * v0 + v1 * v1;
    for (int off = 32; off; off >>= 1) {
        s1 += __shfl_xor(s1, off, 64);
        s2 += __shfl_xor(s2, off, 64);
    }
    __shared__ float red[8];
    int w = t >> 6, lane = t & 63;
    if (lane == 0) { red[w] = s1; red[4 + w] = s2; }
    __syncthreads();
    float sum = red[0] + red[1] + red[2] + red[3];
    float ssq = red[4] + red[5] + red[6] + red[7];
    float mean = sum * (1.f / D);
    float var = ssq * (1.f / D) - mean * mean;
    float rstd = rsqrtf(var + EPS);
    float r0 = (v0 - mean) * rstd * g[t] + be[t];
    float r1 = (v1 - mean) * rstd * g[t + 256] + be[t + 256];
    out[row * D + t] = r0;
    out[row * D + t + 256] = r1;
    if (WB) {
        outb[row * D + t] = f2bf(r0);
        outb[row * D + t + 256] = f2bf(r1);
    }
}

// ---------------------------------------------------------------------------
extern "C" void kernel_launch(void* const* d_in, const int* in_sizes, int n_in,
                              void* d_out, int out_size, void* d_ws, size_t ws_size,
                              hipStream_t stream)
{
    const float* src      = (const float*)d_in[0];
    const int*   rec_idx  = (const int*)d_in[1];
    const int*   cac_idx  = (const int*)d_in[2];
    const float* k_cached = (const float*)d_in[3];
    const float* v_cached = (const float*)d_in[4];
    const float* in_w     = (const float*)d_in[5];
    const float* in_b     = (const float*)d_in[6];
    const float* out_w    = (const float*)d_in[7];
    const float* out_b    = (const float*)d_in[8];
    const float* w1       = (const float*)d_in[9];
    const float* b1       = (const float*)d_in[10];
    const float* w2       = (const float*)d_in[11];
    const float* b2       = (const float*)d_in[12];
    const float* n1w      = (const float*)d_in[13];
    const float* n1b      = (const float*)d_in[14];
    const float* n2w      = (const float*)d_in[15];
    const float* n2b      = (const float*)d_in[16];

    short* SRCb = (short*)d_ws;              // 3145728
    short* WIb  = SRCb + 3145728;            // 786432
    short* WOb  = WIb  + 786432;             // 262144
    short* W1b  = WOb  + 262144;             // 1048576
    short* W2b  = W1b  + 1048576;            // 1048576
    short* Qb   = W2b  + 1048576;            // 3145728
    short* KF   = Qb   + 3145728;            // 3145728
    short* VT   = KF   + 3145728;            // 3145728 (V^T [b,h,hd,s])
    short* CTXb = VT   + 3145728;            // 3145728
    short* Xb   = CTXb + 3145728;            // 3145728
    short* HIDb = Xb   + 3145728;            // 12582912 (FFN hidden bf16)
    short* Opart = HIDb;                     // alias: 12582912 sh = NKH*16*S*HD
    float* AO   = (float*)(HIDb + 12582912); // 3145728 f
    float* X    = AO + 3145728;              // 3145728 f
    float* ML   = X  + 3145728;              // 196608 f (NKH*16*S l-values)
    float* out  = (float*)d_out;

    dim3 blk(256);

    // 0. fused fp32->bf16 conversions (src + 4 weights), one launch
    cvt_all<<<dim3((B * S * D + 3 * D * D + D * D + 2 * DFF * D) / 1024),
              blk, 0, stream>>>(
        src, in_w, out_w, w1, w2, SRCb, WIb, WOb, W1b, W2b);

    // 1+2. fused Q-proj + KV-proj (grid 768 + 384), BK=128
    qkv_proj<<<dim3(1152), blk, 0, stream>>>(
        SRCb, WIb, in_b, Qb, KF, VT, rec_idx);
    // 3. fused cached K/V scatter
    scatter_kv<<<dim3(NKBLK + (SC / 64) * H), blk, 0, stream>>>(
        k_cached, v_cached, cac_idx, KF, VT);
    // 4. attention (split-K=4) + combine
    attn_mfma<<<dim3(B * H * (S / 64), NKH), blk, 0, stream>>>(
        Qb, KF, VT, Opart, ML);
    attn_combine<<<dim3((B * H * S * HD / 4) / 256), blk, 0, stream>>>(
        Opart, ML, CTXb);
    // 5. out projection (BK=128)
    gemm64<0, 0, 0><<<dim3(D / 64, (B * S) / 64), blk, 0, stream>>>(
        CTXb, WOb, out_b, AO, nullptr, B * S, D, D, nullptr);
    // 6. LN1
    ln_kernel<1><<<dim3(B * S), blk, 0, stream>>>(src, AO, n1w, n1b, X, Xb);
    // 7. FFN1 + ReLU
    gemm128<0, 1, 1><<<dim3(DFF / 128, (B * S) / 128), blk, 0, stream>>>(
        Xb, W1b, b1, HIDb, nullptr, B * S, DFF, D, nullptr);
    // 8. FFN2 (BK=128: 16 K-iters instead of 32)
    gemm64<0, 0, 0><<<dim3(D / 64, (B * S) / 64), blk, 0, stream>>>(
        HIDb, W2b, b2, AO, nullptr, B * S, D, DFF, nullptr);
    // 9. LN2 -> d_out
    ln_kernel<0><<<dim3(B * S), blk, 0, stream>>>(X, AO, n2w, n2b, out, nullptr);
}

// Round 16
// 210.201 us; speedup vs baseline: 1.0534x; 1.0534x over previous
//
#include <hip/hip_runtime.h>
#include <hip/hip_bf16.h>
#include <cstdint>
#include <math.h>

#define B 2
#define S 3072
#define D 512
#define H 8
#define HD 64
#define DFF 2048
#define R 768
#define SC (S - R)
#define EPS 1e-5f
#define QSCALE 0.1803368801111137f   // log2(e)/sqrt(64) folded into Q
#define NKH 4                        // split-K factor

typedef __attribute__((ext_vector_type(8))) short s8v;   // 8 x bf16 (4 VGPR)
typedef __attribute__((ext_vector_type(4))) short s4v;   // 4 x bf16 (2 VGPR)
typedef __attribute__((ext_vector_type(4))) float f4v;   // mfma accumulator

__device__ inline short f2bf(float x) {
    __hip_bfloat16 h = __float2bfloat16(x);
    return __builtin_bit_cast(short, h);
}
__device__ inline float bf2f(short s) {
    unsigned int u = (unsigned int)(unsigned short)s << 16;
    return __builtin_bit_cast(float, u);
}
__device__ inline unsigned int pack2bf(float a, float b) {
    return (unsigned int)(unsigned short)f2bf(a) |
           ((unsigned int)(unsigned short)f2bf(b) << 16);
}

// K=16 bf16 MFMA (PV sub-tiles): builtin if present, else raw asm.
__device__ __forceinline__ f4v mfma16(s4v a, s4v b, f4v c) {
#if __has_builtin(__builtin_amdgcn_mfma_f32_16x16x16bf16_1k)
    return __builtin_amdgcn_mfma_f32_16x16x16bf16_1k(a, b, c, 0, 0, 0);
#else
    asm("v_mfma_f32_16x16x16_bf16 %0, %1, %2, %0" : "+v"(c) : "v"(a), "v"(b));
    return c;
#endif
}

// global -> LDS direct 16B load
__device__ __forceinline__ void gload16(const short* g, short* l) {
    auto l3 = reinterpret_cast<__attribute__((address_space(3))) short*>(
        reinterpret_cast<uintptr_t>(l));
    auto g1 = reinterpret_cast<const __attribute__((address_space(1))) short*>(
        reinterpret_cast<uintptr_t>(g));
    __builtin_amdgcn_global_load_lds(g1, l3, 16, 0, 0);
}

// ---------------------------------------------------------------------------
// Fused fp32 -> bf16 conversion: src + all 4 weight matrices, one launch.
// ---------------------------------------------------------------------------
__global__ __launch_bounds__(256) void cvt_all(
    const float* __restrict__ src, const float* __restrict__ w_in,
    const float* __restrict__ w_out, const float* __restrict__ w_1,
    const float* __restrict__ w_2,
    short* __restrict__ o_src, short* __restrict__ o_in,
    short* __restrict__ o_out, short* __restrict__ o_1,
    short* __restrict__ o_2)
{
    int i = (blockIdx.x * 256 + threadIdx.x) * 4;
    const int nS = B * S * D;
    const int n0 = nS + 3 * D * D, n1 = n0 + D * D, n2 = n1 + DFF * D;
    const int n3 = n2 + D * DFF;
    if (i >= n3) return;
    const float* sp; short* dp; int off;
    if (i < nS)      { sp = src;   dp = o_src; off = i; }
    else if (i < n0) { sp = w_in;  dp = o_in;  off = i - nS; }
    else if (i < n1) { sp = w_out; dp = o_out; off = i - n0; }
    else if (i < n2) { sp = w_1;   dp = o_1;   off = i - n1; }
    else             { sp = w_2;   dp = o_2;   off = i - n2; }
    float4 v = *(const float4*)(sp + off);
    short4 o = { f2bf(v.x), f2bf(v.y), f2bf(v.z), f2bf(v.w) };
    *(short4*)(dp + off) = o;
}

// ---------------------------------------------------------------------------
// 128x128 bf16 MFMA GEMM (m97 structure) — verified.  Used for FFN1 only.
// ---------------------------------------------------------------------------
template<int MODE, int RELU, int OUTBF>
__global__ __launch_bounds__(256) void gemm128(
    const short* __restrict__ A, const short* __restrict__ W,
    const float* __restrict__ bias, void* __restrict__ C0v,
    void* __restrict__ C1v, int M, int N, int K,
    const int* __restrict__ gather_idx)
{
    __shared__ short Al[128 * 32];
    __shared__ short Bl[128 * 32];
    const int t = threadIdx.x;
    const int bm = blockIdx.y * 128, bn = blockIdx.x * 128;
    const int lane = t & 63, w = t >> 6;
    const int wm = (w >> 1) * 64, wn = (w & 1) * 64;
    const int lr = lane & 15, lk = lane >> 4;

    const int q1 = t, q2 = t + 256;
    const int r1 = q1 >> 2, c1 = (q1 & 3) ^ (r1 & 3);
    const int r2 = q2 >> 2, c2 = (q2 & 3) ^ (r2 & 3);
    long ga1 = (long)(bm + r1) * K + c1 * 8;
    long ga2 = (long)(bm + r2) * K + c2 * 8;
    const long gb1 = (long)(bn + r1) * K + c1 * 8;
    const long gb2 = (long)(bn + r2) * K + c2 * 8;

    f4v acc[4][4] = {};

    for (int k0 = 0; k0 < K; k0 += 32) {
        __syncthreads();
        gload16(A + ga1 + k0, Al + q1 * 8);
        gload16(A + ga2 + k0, Al + q2 * 8);
        gload16(W + gb1 + k0, Bl + q1 * 8);
        gload16(W + gb2 + k0, Bl + q2 * 8);
        __syncthreads();

        s8v af[4], bf[4];
#pragma unroll
        for (int mi = 0; mi < 4; mi++) {
            int ra = wm + mi * 16 + lr;
            af[mi] = *(const s8v*)&Al[ra * 32 + ((lk ^ (ra & 3)) * 8)];
        }
#pragma unroll
        for (int ni = 0; ni < 4; ni++) {
            int rb = wn + ni * 16 + lr;
            bf[ni] = *(const s8v*)&Bl[rb * 32 + ((lk ^ (rb & 3)) * 8)];
        }
#pragma unroll
        for (int mi = 0; mi < 4; mi++)
#pragma unroll
            for (int ni = 0; ni < 4; ni++)
                acc[mi][ni] = __builtin_amdgcn_mfma_f32_16x16x32_bf16(
                    af[mi], bf[ni], acc[mi][ni], 0, 0, 0);
    }

#pragma unroll
    for (int mi = 0; mi < 4; mi++) {
#pragma unroll
        for (int ni = 0; ni < 4; ni++) {
#pragma unroll
            for (int i = 0; i < 4; i++) {
                int m = bm + wm + mi * 16 + lk * 4 + i;
                int n = bn + wn + ni * 16 + lr;
                float v = acc[mi][ni][i] + bias[n];
                if (RELU) v = fmaxf(v, 0.f);
                if (OUTBF) ((short*)C0v)[(long)m * N + n] = f2bf(v);
                else       ((float*)C0v)[(long)m * N + n] = v;
            }
        }
    }
}

// ---------------------------------------------------------------------------
// 64x64 bf16 MFMA GEMM body (BK=64), verified R13/R14.  Called by wrappers.
// ---------------------------------------------------------------------------
template<int MODE, int RELU, int OUTBF>
__device__ __forceinline__ void gemm64_body(
    const short* __restrict__ A, const short* __restrict__ W,
    const float* __restrict__ bias, void* __restrict__ C0v,
    void* __restrict__ C1v, int M, int N, int K,
    const int* __restrict__ gather_idx, int bm, int bn,
    short* Al, short* Bl)
{
    const int t = threadIdx.x;
    const int lane = t & 63, w = t >> 6;
    const int wm = (w >> 1) * 32, wn = (w & 1) * 32;
    const int lr = lane & 15, lk = lane >> 4;

    const int cq1 = t, cq2 = t + 256;
    const int r1 = cq1 >> 3, s1 = (cq1 & 7) ^ (r1 & 7);
    const int r2 = cq2 >> 3, s2 = (cq2 & 7) ^ (r2 & 7);
    long ga1, ga2;
    if (MODE == 2) {
        int m1 = bm + r1; int b1 = m1 >= R; int i1 = m1 - b1 * R;
        ga1 = ((long)b1 * S + gather_idx[i1]) * K + s1 * 8;
        int m2 = bm + r2; int b2 = m2 >= R; int i2 = m2 - b2 * R;
        ga2 = ((long)b2 * S + gather_idx[i2]) * K + s2 * 8;
    } else {
        ga1 = (long)(bm + r1) * K + s1 * 8;
        ga2 = (long)(bm + r2) * K + s2 * 8;
    }
    const long gb1 = (long)(bn + r1) * K + s1 * 8;
    const long gb2 = (long)(bn + r2) * K + s2 * 8;

    f4v acc[2][2] = {};

    for (int k0 = 0; k0 < K; k0 += 64) {
        __syncthreads();
        gload16(A + ga1 + k0, Al + cq1 * 8);
        gload16(A + ga2 + k0, Al + cq2 * 8);
        gload16(W + gb1 + k0, Bl + cq1 * 8);
        gload16(W + gb2 + k0, Bl + cq2 * 8);
        __syncthreads();

#pragma unroll
        for (int ks = 0; ks < 2; ks++) {
            s8v af[2], bf[2];
#pragma unroll
            for (int mi = 0; mi < 2; mi++) {
                int ra = wm + mi * 16 + lr;
                af[mi] = *(const s8v*)&Al[ra * 64 + (((ks * 4 + lk) ^ (ra & 7)) * 8)];
            }
#pragma unroll
            for (int ni = 0; ni < 2; ni++) {
                int rb = wn + ni * 16 + lr;
                bf[ni] = *(const s8v*)&Bl[rb * 64 + (((ks * 4 + lk) ^ (rb & 7)) * 8)];
            }
#pragma unroll
            for (int mi = 0; mi < 2; mi++)
#pragma unroll
                for (int ni = 0; ni < 2; ni++)
                    acc[mi][ni] = __builtin_amdgcn_mfma_f32_16x16x32_bf16(
                        af[mi], bf[ni], acc[mi][ni], 0, 0, 0);
        }
    }

#pragma unroll
    for (int mi = 0; mi < 2; mi++) {
#pragma unroll
        for (int ni = 0; ni < 2; ni++) {
#pragma unroll
            for (int i = 0; i < 4; i++) {
                int m = bm + wm + mi * 16 + lk * 4 + i;
                int n = bn + wn + ni * 16 + lr;
                float v = acc[mi][ni][i] + bias[n];
                if (RELU) v = fmaxf(v, 0.f);
                if (MODE == 0) {
                    if (OUTBF) ((short*)C0v)[(long)m * N + n] = f2bf(v);
                    else       ((float*)C0v)[(long)m * N + n] = v;
                } else if (MODE == 1) {     // Q scatter (pre-scaled) -> bf16
                    int b = m >= S; int s = m - b * S;
                    int h = n >> 6, hd = n & 63;
                    ((short*)C0v)[(((long)(b * H + h)) * S + s) * HD + hd] =
                        f2bf(v * QSCALE);
                } else {                    // K row-major / V transposed
                    int b = m >= R; int i2 = m - b * R;
                    int s = gather_idx[i2];
                    int c = n;
                    if (c < D) {
                        int h = c >> 6, hd = c & 63;
                        ((short*)C0v)[(((long)(b * H + h)) * S + s) * HD + hd] = f2bf(v);
                    } else {
                        c -= D;
                        int h = c >> 6, hd = c & 63;
                        ((short*)C1v)[(((long)(b * H + h)) * HD + hd) * S + s] = f2bf(v);
                    }
                }
            }
        }
    }
}

// plain gemm64 wrapper (out-proj, FFN2)
template<int MODE, int RELU, int OUTBF>
__global__ __launch_bounds__(256) void gemm64(
    const short* __restrict__ A, const short* __restrict__ W,
    const float* __restrict__ bias, void* __restrict__ C0v,
    void* __restrict__ C1v, int M, int N, int K,
    const int* __restrict__ gather_idx)
{
    __shared__ short Al[64 * 64];
    __shared__ short Bl[64 * 64];
    gemm64_body<MODE, RELU, OUTBF>(A, W, bias, C0v, C1v, M, N, K, gather_idx,
                                   blockIdx.y * 64, blockIdx.x * 64, Al, Bl);
}

// fused Q-proj + KV-proj: blocks [0,768) do Q tiles, [768,1152) do KV tiles.
__global__ __launch_bounds__(256) void qkv_proj(
    const short* __restrict__ SRCb, const short* __restrict__ WIb,
    const float* __restrict__ in_b, short* __restrict__ Qb,
    short* __restrict__ KF, short* __restrict__ VT,
    const int* __restrict__ rec_idx)
{
    __shared__ short Al[64 * 64];
    __shared__ short Bl[64 * 64];
    int g = blockIdx.x;
    if (g < (B * S / 64) * (D / 64)) {          // 96*8 = 768 Q tiles
        int bn = (g & 7) * 64, bm = (g >> 3) * 64;
        gemm64_body<1, 0, 0>(SRCb, WIb, in_b, Qb, nullptr,
                             B * S, D, D, rec_idx, bm, bn, Al, Bl);
    } else {                                    // 24*16 = 384 KV tiles
        int gg = g - 768;
        int bn = (gg & 15) * 64, bm = (gg >> 4) * 64;
        gemm64_body<2, 0, 0>(SRCb, WIb + D * D, in_b + D, KF, VT,
                             B * R, 2 * D, D, rec_idx, bm, bn, Al, Bl);
    }
}

// ---------------------------------------------------------------------------
// Fused cached-K + cached-V^T scatter (one launch).
// ---------------------------------------------------------------------------
#define NKBLK ((H * SC * HD) / 256)             // 4608
__global__ __launch_bounds__(256) void scatter_kv(
    const float* __restrict__ kc, const float* __restrict__ vc,
    const int* __restrict__ cidx, short* __restrict__ kf,
    short* __restrict__ vt)
{
    int blk = blockIdx.x;
    if (blk < NKBLK) {
        long e = (long)blk * 256 + threadIdx.x;
        int hd = e & 63;
        long tmp = e >> 6;
        int j = (int)(tmp % SC);
        int h = (int)(tmp / SC);
        int s = cidx[j];
        short v = f2bf(kc[e]);
        kf[(((long)(0 * H + h)) * S + s) * HD + hd] = v;
        kf[(((long)(1 * H + h)) * S + s) * HD + hd] = v;
    } else {
        int bb = blk - NKBLK;                   // 0 .. (SC/64)*H-1 = 287
        const int h = bb / (SC / 64);
        const int jblk = bb % (SC / 64);
        const int hd = threadIdx.x & 63, jg = threadIdx.x >> 6;
        const int j0 = jblk * 64 + jg * 16;
#pragma unroll 4
        for (int jj = 0; jj < 16; jj++) {
            int j = j0 + jj;
            int s = cidx[j];
            short v = f2bf(vc[((long)h * SC + j) * HD + hd]);
            vt[(((long)(0 * H + h)) * HD + hd) * S + s] = v;
            vt[(((long)(1 * H + h)) * HD + hd) * S + s] = v;
        }
    }
}

// ---------------------------------------------------------------------------
// MFMA flash attention v5: QBLK=128 (two 64-row groups A/B share K/V staging
// AND K/V LDS fragment reads), KVBLK=64, split-K=4.  Per-group pipeline is
// the verified v4: no max tracking, l-sum on MFMA pipe, zero-relayout PV.
// ---------------------------------------------------------------------------
__global__ __launch_bounds__(256) void attn_mfma(
    const short* __restrict__ Qb, const short* __restrict__ KF,
    const short* __restrict__ VT, short* __restrict__ Opart,
    float* __restrict__ ML)
{
    __shared__ short Ks[64 * 64];
    __shared__ short Vt[64 * 64];
    const int t = threadIdx.x;
    const int lane = t & 63, w = t >> 6;
    const int lr = lane & 15, lk = lane >> 4;
    const int nq = S / 128;                      // 24 q-tiles per (b,h)
    const int qt = blockIdx.x % nq;
    const int bh = blockIdx.x / nq;
    const int kh = blockIdx.y;
    const long base = (long)bh * S;

    const int qrA = qt * 128 + w * 16 + lr;
    const int qrB = qrA + 64;
    const s8v qfA0 = *(const s8v*)&Qb[(base + qrA) * HD + lk * 8];
    const s8v qfA1 = *(const s8v*)&Qb[(base + qrA) * HD + 32 + lk * 8];
    const s8v qfB0 = *(const s8v*)&Qb[(base + qrB) * HD + lk * 8];
    const s8v qfB1 = *(const s8v*)&Qb[(base + qrB) * HD + 32 + lk * 8];

    const int cq1 = t, cq2 = t + 256;
    const int sr1 = cq1 >> 3, sc1 = (cq1 & 7) ^ (sr1 & 7);
    const int sr2 = cq2 >> 3, sc2 = (cq2 & 7) ^ (sr2 & 7);
    const long kb1 = (base + sr1) * HD + sc1 * 8;
    const long kb2 = (base + sr2) * HD + sc2 * 8;
    const long vb1 = ((long)bh * HD + sr1) * S + sc1 * 8;
    const long vb2 = ((long)bh * HD + sr2) * S + sc2 * 8;

    f4v odA[4] = {}, odB[4] = {};
    f4v lsA = {}, lsB = {};
    const s4v ones = { 0x3F80, 0x3F80, 0x3F80, 0x3F80 };  // bf16 1.0 x4

    const int kbeg = kh * (S / NKH), kend = kbeg + S / NKH;
    for (int k0 = kbeg; k0 < kend; k0 += 64) {
        __syncthreads();
        gload16(KF + kb1 + (long)k0 * HD, Ks + cq1 * 8);
        gload16(KF + kb2 + (long)k0 * HD, Ks + cq2 * 8);
        gload16(VT + vb1 + k0, Vt + cq1 * 8);
        gload16(VT + vb2 + k0, Vt + cq2 * 8);
        __syncthreads();

        // QK^T both groups; K frags read once
        f4v scA[4], scB[4];
#pragma unroll
        for (int st = 0; st < 4; st++) {
            const int row = st * 16 + lr;
            s8v kf0 = *(const s8v*)&Ks[row * 64 + ((lk ^ (lr & 7)) * 8)];
            s8v kf1 = *(const s8v*)&Ks[row * 64 + (((4 + lk) ^ (lr & 7)) * 8)];
            f4v a = {};
            a = __builtin_amdgcn_mfma_f32_16x16x32_bf16(kf0, qfA0, a, 0, 0, 0);
            a = __builtin_amdgcn_mfma_f32_16x16x32_bf16(kf1, qfA1, a, 0, 0, 0);
            scA[st] = a;
            f4v b = {};
            b = __builtin_amdgcn_mfma_f32_16x16x32_bf16(kf0, qfB0, b, 0, 0, 0);
            b = __builtin_amdgcn_mfma_f32_16x16x32_bf16(kf1, qfB1, b, 0, 0, 0);
            scB[st] = b;
        }

        // P = exp2(s); l-sum on MFMA pipe (per group)
        s4v paA[4], paB[4];
#pragma unroll
        for (int st = 0; st < 4; st++) {
            float a0 = exp2f(scA[st][0]), a1 = exp2f(scA[st][1]);
            float a2 = exp2f(scA[st][2]), a3 = exp2f(scA[st][3]);
            int2 pwa = { (int)pack2bf(a0, a1), (int)pack2bf(a2, a3) };
            paA[st] = __builtin_bit_cast(s4v, pwa);
            lsA = mfma16(paA[st], ones, lsA);
            float b0 = exp2f(scB[st][0]), b1 = exp2f(scB[st][1]);
            float b2 = exp2f(scB[st][2]), b3 = exp2f(scB[st][3]);
            int2 pwb = { (int)pack2bf(b0, b1), (int)pack2bf(b2, b3) };
            paB[st] = __builtin_bit_cast(s4v, pwb);
            lsB = mfma16(paB[st], ones, lsB);
        }

        // PV both groups; V frags read once
#pragma unroll
        for (int dst = 0; dst < 4; dst++) {
            const int d = dst * 16 + lr;
#pragma unroll
            for (int st = 0; st < 4; st++) {
                int cc = 2 * st + (lk >> 1);
                s4v vf = *(const s4v*)&Vt[d * 64 + ((cc ^ (lr & 7)) * 8) + (lk & 1) * 4];
                odA[dst] = mfma16(paA[st], vf, odA[dst]);
                odB[dst] = mfma16(paB[st], vf, odB[dst]);
            }
        }
    }

    const long pb = ((long)(kh * 16 + bh)) * S;
    if (lr == 0) {
#pragma unroll
        for (int i = 0; i < 4; i++) {
            int q = qt * 128 + w * 16 + lk * 4 + i;
            ML[pb + q] = lsA[i];
            ML[pb + q + 64] = lsB[i];
        }
    }
#pragma unroll
    for (int dst = 0; dst < 4; dst++)
#pragma unroll
        for (int i = 0; i < 4; i++) {
            int q = qt * 128 + w * 16 + lk * 4 + i;
            int d = dst * 16 + lr;
            Opart[(pb + q) * HD + d] = f2bf(odA[dst][i]);
            Opart[(pb + q + 64) * HD + d] = f2bf(odB[dst][i]);
        }
}

// ---------------------------------------------------------------------------
// Combine NKH key-slice bf16 partials: O = sum O_i / sum l_i -> bf16 ctx.
// ---------------------------------------------------------------------------
__global__ __launch_bounds__(256) void attn_combine(
    const short* __restrict__ Opart, const float* __restrict__ ML,
    short* __restrict__ ctxb)
{
    long idx = (long)blockIdx.x * 256 + threadIdx.x;
    long f = idx * 4;
    int d = (int)(f & 63);
    long x = f >> 6;
    int bh = (int)(x / S);
    int q = (int)(x - (long)bh * S);
    float l = 0.f;
    float4 o = {0.f, 0.f, 0.f, 0.f};
#pragma unroll
    for (int kh = 0; kh < NKH; kh++) {
        long xx = x + (long)kh * 16 * S;
        l += ML[xx];
        short4 p = *(const short4*)&Opart[xx * HD + d];
        o.x += bf2f(p.x); o.y += bf2f(p.y);
        o.z += bf2f(p.z); o.w += bf2f(p.w);
    }
    float inv = 1.f / l;
    int b = bh >> 3, h = bh & 7;
    short4 r;
    r.x = f2bf(o.x * inv);
    r.y = f2bf(o.y * inv);
    r.z = f2bf(o.z * inv);
    r.w = f2bf(o.w * inv);
    *(short4*)&ctxb[((long)(b * S + q)) * D + h * HD + d] = r;
}

// ---------------------------------------------------------------------------
template<int WB>
__global__ __launch_bounds__(256) void ln_kernel(
    const float* __restrict__ a, const float* __restrict__ r,
    const float* __restrict__ g, const float* __restrict__ be,
    float* __restrict__ out, short* __restrict__ outb)
{
    const long row = blockIdx.x;
    const int t = threadIdx.x;
    const float* pa = a + row * D;
    const float* pr = r + row * D;
    float v0 = pa[t] + pr[t];
    float v1 = pa[t + 256] + pr[t + 256];
    float s1 = v0 + v1, s2 = v0 * v0 + v1 * v1;
    for (int off = 32; off; off >>= 1) {
        s1 += __shfl_xor(s1, off, 64);
        s2 += __shfl_xor(s2, off, 64);
    }
    __shared__ float red[8];
    int w = t >> 6, lane = t & 63;
    if (lane == 0) { red[w] = s1; red[4 + w] = s2; }
    __syncthreads();
    float sum = red[0] + red[1] + red[2] + red[3];
    float ssq = red[4] + red[5] + red[6] + red[7];
    float mean = sum * (1.f / D);
    float var = ssq * (1.f / D) - mean * mean;
    float rstd = rsqrtf(var + EPS);
    float r0 = (v0 - mean) * rstd * g[t] + be[t];
    float r1 = (v1 - mean) * rstd * g[t + 256] + be[t + 256];
    out[row * D + t] = r0;
    out[row * D + t + 256] = r1;
    if (WB) {
        outb[row * D + t] = f2bf(r0);
        outb[row * D + t + 256] = f2bf(r1);
    }
}

// ---------------------------------------------------------------------------
extern "C" void kernel_launch(void* const* d_in, const int* in_sizes, int n_in,
                              void* d_out, int out_size, void* d_ws, size_t ws_size,
                              hipStream_t stream)
{
    const float* src      = (const float*)d_in[0];
    const int*   rec_idx  = (const int*)d_in[1];
    const int*   cac_idx  = (const int*)d_in[2];
    const float* k_cached = (const float*)d_in[3];
    const float* v_cached = (const float*)d_in[4];
    const float* in_w     = (const float*)d_in[5];
    const float* in_b     = (const float*)d_in[6];
    const float* out_w    = (const float*)d_in[7];
    const float* out_b    = (const float*)d_in[8];
    const float* w1       = (const float*)d_in[9];
    const float* b1       = (const float*)d_in[10];
    const float* w2       = (const float*)d_in[11];
    const float* b2       = (const float*)d_in[12];
    const float* n1w      = (const float*)d_in[13];
    const float* n1b      = (const float*)d_in[14];
    const float* n2w      = (const float*)d_in[15];
    const float* n2b      = (const float*)d_in[16];

    short* SRCb = (short*)d_ws;              // 3145728
    short* WIb  = SRCb + 3145728;            // 786432
    short* WOb  = WIb  + 786432;             // 262144
    short* W1b  = WOb  + 262144;             // 1048576
    short* W2b  = W1b  + 1048576;            // 1048576
    short* Qb   = W2b  + 1048576;            // 3145728
    short* KF   = Qb   + 3145728;            // 3145728
    short* VT   = KF   + 3145728;            // 3145728 (V^T [b,h,hd,s])
    short* CTXb = VT   + 3145728;            // 3145728
    short* Xb   = CTXb + 3145728;            // 3145728
    short* HIDb = Xb   + 3145728;            // 12582912 (FFN hidden bf16)
    short* Opart = HIDb;                     // alias: 12582912 sh = NKH*16*S*HD
    float* AO   = (float*)(HIDb + 12582912); // 3145728 f
    float* X    = AO + 3145728;              // 3145728 f
    float* ML   = X  + 3145728;              // 196608 f (NKH*16*S l-values)
    float* out  = (float*)d_out;

    dim3 blk(256);

    // 0. fused fp32->bf16 conversions (src + 4 weights), one launch
    cvt_all<<<dim3((B * S * D + 3 * D * D + D * D + 2 * DFF * D) / 1024),
              blk, 0, stream>>>(
        src, in_w, out_w, w1, w2, SRCb, WIb, WOb, W1b, W2b);

    // 1+2. fused Q-proj + KV-proj (grid 768 + 384), BK=64
    qkv_proj<<<dim3(1152), blk, 0, stream>>>(
        SRCb, WIb, in_b, Qb, KF, VT, rec_idx);
    // 3. fused cached K/V scatter
    scatter_kv<<<dim3(NKBLK + (SC / 64) * H), blk, 0, stream>>>(
        k_cached, v_cached, cac_idx, KF, VT);
    // 4. attention (QBLK=128, split-K=4) + combine
    attn_mfma<<<dim3(B * H * (S / 128), NKH), blk, 0, stream>>>(
        Qb, KF, VT, Opart, ML);
    attn_combine<<<dim3((B * H * S * HD / 4) / 256), blk, 0, stream>>>(
        Opart, ML, CTXb);
    // 5. out projection
    gemm64<0, 0, 0><<<dim3(D / 64, (B * S) / 64), blk, 0, stream>>>(
        CTXb, WOb, out_b, AO, nullptr, B * S, D, D, nullptr);
    // 6. LN1
    ln_kernel<1><<<dim3(B * S), blk, 0, stream>>>(src, AO, n1w, n1b, X, Xb);
    // 7. FFN1 + ReLU
    gemm128<0, 1, 1><<<dim3(DFF / 128, (B * S) / 128), blk, 0, stream>>>(
        Xb, W1b, b1, HIDb, nullptr, B * S, DFF, D, nullptr);
    // 8. FFN2
    gemm64<0, 0, 0><<<dim3(D / 64, (B * S) / 64), blk, 0, stream>>>(
        HIDb, W2b, b2, AO, nullptr, B * S, D, DFF, nullptr);
    // 9. LN2 -> d_out
    ln_kernel<0><<<dim3(B * S), blk, 0, stream>>>(X, AO, n2w, n2b, out, nullptr);
}

// Round 17
// 203.981 us; speedup vs baseline: 1.0855x; 1.0305x over previous
//
#include <hip/hip_runtime.h>
#include <hip/hip_bf16.h>
#include <cstdint>
#include <math.h>

#define B 2
#define S 3072
#define D 512
#define H 8
#define HD 64
#define DFF 2048
#define R 768
#define SC (S - R)
#define EPS 1e-5f
#define QSCALE 0.1803368801111137f   // log2(e)/sqrt(64) folded into Q
#define NKH 4                        // split-K factor

typedef __attribute__((ext_vector_type(8))) short s8v;   // 8 x bf16 (4 VGPR)
typedef __attribute__((ext_vector_type(4))) short s4v;   // 4 x bf16 (2 VGPR)
typedef __attribute__((ext_vector_type(4))) float f4v;   // mfma accumulator

__device__ inline short f2bf(float x) {
    __hip_bfloat16 h = __float2bfloat16(x);
    return __builtin_bit_cast(short, h);
}
__device__ inline float bf2f(short s) {
    unsigned int u = (unsigned int)(unsigned short)s << 16;
    return __builtin_bit_cast(float, u);
}
__device__ inline unsigned int pack2bf(float a, float b) {
    return (unsigned int)(unsigned short)f2bf(a) |
           ((unsigned int)(unsigned short)f2bf(b) << 16);
}

// K=16 bf16 MFMA (PV sub-tiles): builtin if present, else raw asm.
__device__ __forceinline__ f4v mfma16(s4v a, s4v b, f4v c) {
#if __has_builtin(__builtin_amdgcn_mfma_f32_16x16x16bf16_1k)
    return __builtin_amdgcn_mfma_f32_16x16x16bf16_1k(a, b, c, 0, 0, 0);
#else
    asm("v_mfma_f32_16x16x16_bf16 %0, %1, %2, %0" : "+v"(c) : "v"(a), "v"(b));
    return c;
#endif
}

// global -> LDS direct 16B load
__device__ __forceinline__ void gload16(const short* g, short* l) {
    auto l3 = reinterpret_cast<__attribute__((address_space(3))) short*>(
        reinterpret_cast<uintptr_t>(l));
    auto g1 = reinterpret_cast<const __attribute__((address_space(1))) short*>(
        reinterpret_cast<uintptr_t>(g));
    __builtin_amdgcn_global_load_lds(g1, l3, 16, 0, 0);
}

// ---------------------------------------------------------------------------
// Fused fp32 -> bf16 conversion: src + all 4 weight matrices, one launch.
// ---------------------------------------------------------------------------
__global__ __launch_bounds__(256) void cvt_all(
    const float* __restrict__ src, const float* __restrict__ w_in,
    const float* __restrict__ w_out, const float* __restrict__ w_1,
    const float* __restrict__ w_2,
    short* __restrict__ o_src, short* __restrict__ o_in,
    short* __restrict__ o_out, short* __restrict__ o_1,
    short* __restrict__ o_2)
{
    int i = (blockIdx.x * 256 + threadIdx.x) * 4;
    const int nS = B * S * D;
    const int n0 = nS + 3 * D * D, n1 = n0 + D * D, n2 = n1 + DFF * D;
    const int n3 = n2 + D * DFF;
    if (i >= n3) return;
    const float* sp; short* dp; int off;
    if (i < nS)      { sp = src;   dp = o_src; off = i; }
    else if (i < n0) { sp = w_in;  dp = o_in;  off = i - nS; }
    else if (i < n1) { sp = w_out; dp = o_out; off = i - n0; }
    else if (i < n2) { sp = w_1;   dp = o_1;   off = i - n1; }
    else             { sp = w_2;   dp = o_2;   off = i - n2; }
    float4 v = *(const float4*)(sp + off);
    short4 o = { f2bf(v.x), f2bf(v.y), f2bf(v.z), f2bf(v.w) };
    *(short4*)(dp + off) = o;
}

// ---------------------------------------------------------------------------
// 128x128 bf16 MFMA GEMM (m97 structure) — verified.  Used for FFN1 only.
// ---------------------------------------------------------------------------
template<int MODE, int RELU, int OUTBF>
__global__ __launch_bounds__(256) void gemm128(
    const short* __restrict__ A, const short* __restrict__ W,
    const float* __restrict__ bias, void* __restrict__ C0v,
    void* __restrict__ C1v, int M, int N, int K,
    const int* __restrict__ gather_idx)
{
    __shared__ short Al[128 * 32];
    __shared__ short Bl[128 * 32];
    const int t = threadIdx.x;
    const int bm = blockIdx.y * 128, bn = blockIdx.x * 128;
    const int lane = t & 63, w = t >> 6;
    const int wm = (w >> 1) * 64, wn = (w & 1) * 64;
    const int lr = lane & 15, lk = lane >> 4;

    const int q1 = t, q2 = t + 256;
    const int r1 = q1 >> 2, c1 = (q1 & 3) ^ (r1 & 3);
    const int r2 = q2 >> 2, c2 = (q2 & 3) ^ (r2 & 3);
    long ga1 = (long)(bm + r1) * K + c1 * 8;
    long ga2 = (long)(bm + r2) * K + c2 * 8;
    const long gb1 = (long)(bn + r1) * K + c1 * 8;
    const long gb2 = (long)(bn + r2) * K + c2 * 8;

    f4v acc[4][4] = {};

    for (int k0 = 0; k0 < K; k0 += 32) {
        __syncthreads();
        gload16(A + ga1 + k0, Al + q1 * 8);
        gload16(A + ga2 + k0, Al + q2 * 8);
        gload16(W + gb1 + k0, Bl + q1 * 8);
        gload16(W + gb2 + k0, Bl + q2 * 8);
        __syncthreads();

        s8v af[4], bf[4];
#pragma unroll
        for (int mi = 0; mi < 4; mi++) {
            int ra = wm + mi * 16 + lr;
            af[mi] = *(const s8v*)&Al[ra * 32 + ((lk ^ (ra & 3)) * 8)];
        }
#pragma unroll
        for (int ni = 0; ni < 4; ni++) {
            int rb = wn + ni * 16 + lr;
            bf[ni] = *(const s8v*)&Bl[rb * 32 + ((lk ^ (rb & 3)) * 8)];
        }
#pragma unroll
        for (int mi = 0; mi < 4; mi++)
#pragma unroll
            for (int ni = 0; ni < 4; ni++)
                acc[mi][ni] = __builtin_amdgcn_mfma_f32_16x16x32_bf16(
                    af[mi], bf[ni], acc[mi][ni], 0, 0, 0);
    }

#pragma unroll
    for (int mi = 0; mi < 4; mi++) {
#pragma unroll
        for (int ni = 0; ni < 4; ni++) {
#pragma unroll
            for (int i = 0; i < 4; i++) {
                int m = bm + wm + mi * 16 + lk * 4 + i;
                int n = bn + wn + ni * 16 + lr;
                float v = acc[mi][ni][i] + bias[n];
                if (RELU) v = fmaxf(v, 0.f);
                if (OUTBF) ((short*)C0v)[(long)m * N + n] = f2bf(v);
                else       ((float*)C0v)[(long)m * N + n] = v;
            }
        }
    }
}

// ---------------------------------------------------------------------------
// 64x64 bf16 MFMA GEMM body (BK=64), verified R13/R14.  Called by wrappers.
// ---------------------------------------------------------------------------
template<int MODE, int RELU, int OUTBF>
__device__ __forceinline__ void gemm64_body(
    const short* __restrict__ A, const short* __restrict__ W,
    const float* __restrict__ bias, void* __restrict__ C0v,
    void* __restrict__ C1v, int M, int N, int K,
    const int* __restrict__ gather_idx, int bm, int bn,
    short* Al, short* Bl)
{
    const int t = threadIdx.x;
    const int lane = t & 63, w = t >> 6;
    const int wm = (w >> 1) * 32, wn = (w & 1) * 32;
    const int lr = lane & 15, lk = lane >> 4;

    const int cq1 = t, cq2 = t + 256;
    const int r1 = cq1 >> 3, s1 = (cq1 & 7) ^ (r1 & 7);
    const int r2 = cq2 >> 3, s2 = (cq2 & 7) ^ (r2 & 7);
    long ga1, ga2;
    if (MODE == 2) {
        int m1 = bm + r1; int b1 = m1 >= R; int i1 = m1 - b1 * R;
        ga1 = ((long)b1 * S + gather_idx[i1]) * K + s1 * 8;
        int m2 = bm + r2; int b2 = m2 >= R; int i2 = m2 - b2 * R;
        ga2 = ((long)b2 * S + gather_idx[i2]) * K + s2 * 8;
    } else {
        ga1 = (long)(bm + r1) * K + s1 * 8;
        ga2 = (long)(bm + r2) * K + s2 * 8;
    }
    const long gb1 = (long)(bn + r1) * K + s1 * 8;
    const long gb2 = (long)(bn + r2) * K + s2 * 8;

    f4v acc[2][2] = {};

    for (int k0 = 0; k0 < K; k0 += 64) {
        __syncthreads();
        gload16(A + ga1 + k0, Al + cq1 * 8);
        gload16(A + ga2 + k0, Al + cq2 * 8);
        gload16(W + gb1 + k0, Bl + cq1 * 8);
        gload16(W + gb2 + k0, Bl + cq2 * 8);
        __syncthreads();

#pragma unroll
        for (int ks = 0; ks < 2; ks++) {
            s8v af[2], bf[2];
#pragma unroll
            for (int mi = 0; mi < 2; mi++) {
                int ra = wm + mi * 16 + lr;
                af[mi] = *(const s8v*)&Al[ra * 64 + (((ks * 4 + lk) ^ (ra & 7)) * 8)];
            }
#pragma unroll
            for (int ni = 0; ni < 2; ni++) {
                int rb = wn + ni * 16 + lr;
                bf[ni] = *(const s8v*)&Bl[rb * 64 + (((ks * 4 + lk) ^ (rb & 7)) * 8)];
            }
#pragma unroll
            for (int mi = 0; mi < 2; mi++)
#pragma unroll
                for (int ni = 0; ni < 2; ni++)
                    acc[mi][ni] = __builtin_amdgcn_mfma_f32_16x16x32_bf16(
                        af[mi], bf[ni], acc[mi][ni], 0, 0, 0);
        }
    }

#pragma unroll
    for (int mi = 0; mi < 2; mi++) {
#pragma unroll
        for (int ni = 0; ni < 2; ni++) {
#pragma unroll
            for (int i = 0; i < 4; i++) {
                int m = bm + wm + mi * 16 + lk * 4 + i;
                int n = bn + wn + ni * 16 + lr;
                float v = acc[mi][ni][i] + bias[n];
                if (RELU) v = fmaxf(v, 0.f);
                if (MODE == 0) {
                    if (OUTBF) ((short*)C0v)[(long)m * N + n] = f2bf(v);
                    else       ((float*)C0v)[(long)m * N + n] = v;
                } else if (MODE == 1) {     // Q scatter (pre-scaled) -> bf16
                    int b = m >= S; int s = m - b * S;
                    int h = n >> 6, hd = n & 63;
                    ((short*)C0v)[(((long)(b * H + h)) * S + s) * HD + hd] =
                        f2bf(v * QSCALE);
                } else {                    // K row-major / V transposed
                    int b = m >= R; int i2 = m - b * R;
                    int s = gather_idx[i2];
                    int c = n;
                    if (c < D) {
                        int h = c >> 6, hd = c & 63;
                        ((short*)C0v)[(((long)(b * H + h)) * S + s) * HD + hd] = f2bf(v);
                    } else {
                        c -= D;
                        int h = c >> 6, hd = c & 63;
                        ((short*)C1v)[(((long)(b * H + h)) * HD + hd) * S + s] = f2bf(v);
                    }
                }
            }
        }
    }
}

// plain gemm64 wrapper (out-proj, FFN2)
template<int MODE, int RELU, int OUTBF>
__global__ __launch_bounds__(256) void gemm64(
    const short* __restrict__ A, const short* __restrict__ W,
    const float* __restrict__ bias, void* __restrict__ C0v,
    void* __restrict__ C1v, int M, int N, int K,
    const int* __restrict__ gather_idx)
{
    __shared__ short Al[64 * 64];
    __shared__ short Bl[64 * 64];
    gemm64_body<MODE, RELU, OUTBF>(A, W, bias, C0v, C1v, M, N, K, gather_idx,
                                   blockIdx.y * 64, blockIdx.x * 64, Al, Bl);
}

// ---------------------------------------------------------------------------
// Fused Q-proj + KV-proj + cached K/V scatter, one launch.
// blocks [0,768): Q tiles.  [768,1152): KV tiles.
// [1152,5760): cached-K scatter.  [5760,6048): cached-V^T scatter.
// ---------------------------------------------------------------------------
#define NKBLK ((H * SC * HD) / 256)             // 4608
__global__ __launch_bounds__(256) void qkv_scatter(
    const short* __restrict__ SRCb, const short* __restrict__ WIb,
    const float* __restrict__ in_b, short* __restrict__ Qb,
    short* __restrict__ KF, short* __restrict__ VT,
    const int* __restrict__ rec_idx,
    const float* __restrict__ kc, const float* __restrict__ vc,
    const int* __restrict__ cidx)
{
    __shared__ short Al[64 * 64];
    __shared__ short Bl[64 * 64];
    int g = blockIdx.x;
    if (g < 768) {                              // Q tiles
        int bn = (g & 7) * 64, bm = (g >> 3) * 64;
        gemm64_body<1, 0, 0>(SRCb, WIb, in_b, Qb, nullptr,
                             B * S, D, D, rec_idx, bm, bn, Al, Bl);
    } else if (g < 1152) {                      // KV tiles
        int gg = g - 768;
        int bn = (gg & 15) * 64, bm = (gg >> 4) * 64;
        gemm64_body<2, 0, 0>(SRCb, WIb + D * D, in_b + D, KF, VT,
                             B * R, 2 * D, D, rec_idx, bm, bn, Al, Bl);
    } else if (g < 1152 + NKBLK) {              // cached-K scatter
        long e = (long)(g - 1152) * 256 + threadIdx.x;
        int hd = e & 63;
        long tmp = e >> 6;
        int j = (int)(tmp % SC);
        int h = (int)(tmp / SC);
        int s = cidx[j];
        short v = f2bf(kc[e]);
        KF[(((long)(0 * H + h)) * S + s) * HD + hd] = v;
        KF[(((long)(1 * H + h)) * S + s) * HD + hd] = v;
    } else {                                    // cached-V^T scatter
        int bb = g - 1152 - NKBLK;              // 0..287
        const int h = bb / (SC / 64);
        const int jblk = bb % (SC / 64);
        const int hd = threadIdx.x & 63, jg = threadIdx.x >> 6;
        const int j0 = jblk * 64 + jg * 16;
#pragma unroll 4
        for (int jj = 0; jj < 16; jj++) {
            int j = j0 + jj;
            int s = cidx[j];
            short v = f2bf(vc[((long)h * SC + j) * HD + hd]);
            VT[(((long)(0 * H + h)) * HD + hd) * S + s] = v;
            VT[(((long)(1 * H + h)) * HD + hd) * S + s] = v;
        }
    }
}

// ---------------------------------------------------------------------------
// MFMA flash attention v5 (verified R16): QBLK=128, split-K=4.
// ---------------------------------------------------------------------------
__global__ __launch_bounds__(256) void attn_mfma(
    const short* __restrict__ Qb, const short* __restrict__ KF,
    const short* __restrict__ VT, short* __restrict__ Opart,
    float* __restrict__ ML)
{
    __shared__ short Ks[64 * 64];
    __shared__ short Vt[64 * 64];
    const int t = threadIdx.x;
    const int lane = t & 63, w = t >> 6;
    const int lr = lane & 15, lk = lane >> 4;
    const int nq = S / 128;
    const int qt = blockIdx.x % nq;
    const int bh = blockIdx.x / nq;
    const int kh = blockIdx.y;
    const long base = (long)bh * S;

    const int qrA = qt * 128 + w * 16 + lr;
    const int qrB = qrA + 64;
    const s8v qfA0 = *(const s8v*)&Qb[(base + qrA) * HD + lk * 8];
    const s8v qfA1 = *(const s8v*)&Qb[(base + qrA) * HD + 32 + lk * 8];
    const s8v qfB0 = *(const s8v*)&Qb[(base + qrB) * HD + lk * 8];
    const s8v qfB1 = *(const s8v*)&Qb[(base + qrB) * HD + 32 + lk * 8];

    const int cq1 = t, cq2 = t + 256;
    const int sr1 = cq1 >> 3, sc1 = (cq1 & 7) ^ (sr1 & 7);
    const int sr2 = cq2 >> 3, sc2 = (cq2 & 7) ^ (sr2 & 7);
    const long kb1 = (base + sr1) * HD + sc1 * 8;
    const long kb2 = (base + sr2) * HD + sc2 * 8;
    const long vb1 = ((long)bh * HD + sr1) * S + sc1 * 8;
    const long vb2 = ((long)bh * HD + sr2) * S + sc2 * 8;

    f4v odA[4] = {}, odB[4] = {};
    f4v lsA = {}, lsB = {};
    const s4v ones = { 0x3F80, 0x3F80, 0x3F80, 0x3F80 };  // bf16 1.0 x4

    const int kbeg = kh * (S / NKH), kend = kbeg + S / NKH;
    for (int k0 = kbeg; k0 < kend; k0 += 64) {
        __syncthreads();
        gload16(KF + kb1 + (long)k0 * HD, Ks + cq1 * 8);
        gload16(KF + kb2 + (long)k0 * HD, Ks + cq2 * 8);
        gload16(VT + vb1 + k0, Vt + cq1 * 8);
        gload16(VT + vb2 + k0, Vt + cq2 * 8);
        __syncthreads();

        f4v scA[4], scB[4];
#pragma unroll
        for (int st = 0; st < 4; st++) {
            const int row = st * 16 + lr;
            s8v kf0 = *(const s8v*)&Ks[row * 64 + ((lk ^ (lr & 7)) * 8)];
            s8v kf1 = *(const s8v*)&Ks[row * 64 + (((4 + lk) ^ (lr & 7)) * 8)];
            f4v a = {};
            a = __builtin_amdgcn_mfma_f32_16x16x32_bf16(kf0, qfA0, a, 0, 0, 0);
            a = __builtin_amdgcn_mfma_f32_16x16x32_bf16(kf1, qfA1, a, 0, 0, 0);
            scA[st] = a;
            f4v b = {};
            b = __builtin_amdgcn_mfma_f32_16x16x32_bf16(kf0, qfB0, b, 0, 0, 0);
            b = __builtin_amdgcn_mfma_f32_16x16x32_bf16(kf1, qfB1, b, 0, 0, 0);
            scB[st] = b;
        }

        s4v paA[4], paB[4];
#pragma unroll
        for (int st = 0; st < 4; st++) {
            float a0 = exp2f(scA[st][0]), a1 = exp2f(scA[st][1]);
            float a2 = exp2f(scA[st][2]), a3 = exp2f(scA[st][3]);
            int2 pwa = { (int)pack2bf(a0, a1), (int)pack2bf(a2, a3) };
            paA[st] = __builtin_bit_cast(s4v, pwa);
            lsA = mfma16(paA[st], ones, lsA);
            float b0 = exp2f(scB[st][0]), b1 = exp2f(scB[st][1]);
            float b2 = exp2f(scB[st][2]), b3 = exp2f(scB[st][3]);
            int2 pwb = { (int)pack2bf(b0, b1), (int)pack2bf(b2, b3) };
            paB[st] = __builtin_bit_cast(s4v, pwb);
            lsB = mfma16(paB[st], ones, lsB);
        }

#pragma unroll
        for (int dst = 0; dst < 4; dst++) {
            const int d = dst * 16 + lr;
#pragma unroll
            for (int st = 0; st < 4; st++) {
                int cc = 2 * st + (lk >> 1);
                s4v vf = *(const s4v*)&Vt[d * 64 + ((cc ^ (lr & 7)) * 8) + (lk & 1) * 4];
                odA[dst] = mfma16(paA[st], vf, odA[dst]);
                odB[dst] = mfma16(paB[st], vf, odB[dst]);
            }
        }
    }

    const long pb = ((long)(kh * 16 + bh)) * S;
    if (lr == 0) {
#pragma unroll
        for (int i = 0; i < 4; i++) {
            int q = qt * 128 + w * 16 + lk * 4 + i;
            ML[pb + q] = lsA[i];
            ML[pb + q + 64] = lsB[i];
        }
    }
#pragma unroll
    for (int dst = 0; dst < 4; dst++)
#pragma unroll
        for (int i = 0; i < 4; i++) {
            int q = qt * 128 + w * 16 + lk * 4 + i;
            int d = dst * 16 + lr;
            Opart[(pb + q) * HD + d] = f2bf(odA[dst][i]);
            Opart[(pb + q + 64) * HD + d] = f2bf(odB[dst][i]);
        }
}

// ---------------------------------------------------------------------------
// Combine NKH key-slice bf16 partials: O = sum O_i / sum l_i -> bf16 ctx.
// ---------------------------------------------------------------------------
__global__ __launch_bounds__(256) void attn_combine(
    const short* __restrict__ Opart, const float* __restrict__ ML,
    short* __restrict__ ctxb)
{
    long idx = (long)blockIdx.x * 256 + threadIdx.x;
    long f = idx * 4;
    int d = (int)(f & 63);
    long x = f >> 6;
    int bh = (int)(x / S);
    int q = (int)(x - (long)bh * S);
    float l = 0.f;
    float4 o = {0.f, 0.f, 0.f, 0.f};
#pragma unroll
    for (int kh = 0; kh < NKH; kh++) {
        long xx = x + (long)kh * 16 * S;
        l += ML[xx];
        short4 p = *(const short4*)&Opart[xx * HD + d];
        o.x += bf2f(p.x); o.y += bf2f(p.y);
        o.z += bf2f(p.z); o.w += bf2f(p.w);
    }
    float inv = 1.f / l;
    int b = bh >> 3, h = bh & 7;
    short4 r;
    r.x = f2bf(o.x * inv);
    r.y = f2bf(o.y * inv);
    r.z = f2bf(o.z * inv);
    r.w = f2bf(o.w * inv);
    *(short4*)&ctxb[((long)(b * S + q)) * D + h * HD + d] = r;
}

// ---------------------------------------------------------------------------
// LayerNorm: out = LN(a + r) * g + be.  a: fp32 (AF32=1) or bf16; r: bf16.
// out: fp32 (OUTF32=1) or bf16.
// ---------------------------------------------------------------------------
template<int AF32, int OUTF32>
__global__ __launch_bounds__(256) void ln_kernel(
    const void* __restrict__ av, const short* __restrict__ rv,
    const float* __restrict__ g, const float* __restrict__ be,
    void* __restrict__ outv)
{
    const long row = blockIdx.x;
    const int t = threadIdx.x;
    float a0, a1;
    if (AF32) {
        const float* pa = (const float*)av + row * D;
        a0 = pa[t]; a1 = pa[t + 256];
    } else {
        const short* pa = (const short*)av + row * D;
        a0 = bf2f(pa[t]); a1 = bf2f(pa[t + 256]);
    }
    const short* pr = rv + row * D;
    float v0 = a0 + bf2f(pr[t]);
    float v1 = a1 + bf2f(pr[t + 256]);
    float s1 = v0 + v1, s2 = v0 * v0 + v1 * v1;
    for (int off = 32; off; off >>= 1) {
        s1 += __shfl_xor(s1, off, 64);
        s2 += __shfl_xor(s2, off, 64);
    }
    __shared__ float red[8];
    int w = t >> 6, lane = t & 63;
    if (lane == 0) { red[w] = s1; red[4 + w] = s2; }
    __syncthreads();
    float sum = red[0] + red[1] + red[2] + red[3];
    float ssq = red[4] + red[5] + red[6] + red[7];
    float mean = sum * (1.f / D);
    float var = ssq * (1.f / D) - mean * mean;
    float rstd = rsqrtf(var + EPS);
    float r0 = (v0 - mean) * rstd * g[t] + be[t];
    float r1 = (v1 - mean) * rstd * g[t + 256] + be[t + 256];
    if (OUTF32) {
        float* o = (float*)outv + row * D;
        o[t] = r0; o[t + 256] = r1;
    } else {
        short* o = (short*)outv + row * D;
        o[t] = f2bf(r0); o[t + 256] = f2bf(r1);
    }
}

// ---------------------------------------------------------------------------
extern "C" void kernel_launch(void* const* d_in, const int* in_sizes, int n_in,
                              void* d_out, int out_size, void* d_ws, size_t ws_size,
                              hipStream_t stream)
{
    const float* src      = (const float*)d_in[0];
    const int*   rec_idx  = (const int*)d_in[1];
    const int*   cac_idx  = (const int*)d_in[2];
    const float* k_cached = (const float*)d_in[3];
    const float* v_cached = (const float*)d_in[4];
    const float* in_w     = (const float*)d_in[5];
    const float* in_b     = (const float*)d_in[6];
    const float* out_w    = (const float*)d_in[7];
    const float* out_b    = (const float*)d_in[8];
    const float* w1       = (const float*)d_in[9];
    const float* b1       = (const float*)d_in[10];
    const float* w2       = (const float*)d_in[11];
    const float* b2       = (const float*)d_in[12];
    const float* n1w      = (const float*)d_in[13];
    const float* n1b      = (const float*)d_in[14];
    const float* n2w      = (const float*)d_in[15];
    const float* n2b      = (const float*)d_in[16];

    short* SRCb = (short*)d_ws;              // 3145728
    short* WIb  = SRCb + 3145728;            // 786432
    short* WOb  = WIb  + 786432;             // 262144
    short* W1b  = WOb  + 262144;             // 1048576
    short* W2b  = W1b  + 1048576;            // 1048576
    short* Qb   = W2b  + 1048576;            // 3145728
    short* KF   = Qb   + 3145728;            // 3145728
    short* VT   = KF   + 3145728;            // 3145728 (V^T [b,h,hd,s])
    short* CTXb = VT   + 3145728;            // 3145728
    short* Xb   = CTXb + 3145728;            // 3145728
    short* AOb  = Xb   + 3145728;            // 3145728 (bf16 residual branch)
    short* HIDb = AOb  + 3145728;            // 12582912 (FFN hidden bf16)
    short* Opart = HIDb;                     // alias: 12582912 sh = NKH*16*S*HD
    float* ML   = (float*)(HIDb + 12582912); // 196608 f (NKH*16*S l-values)
    float* out  = (float*)d_out;

    dim3 blk(256);

    // 0. fused fp32->bf16 conversions (src + 4 weights), one launch
    cvt_all<<<dim3((B * S * D + 3 * D * D + D * D + 2 * DFF * D) / 1024),
              blk, 0, stream>>>(
        src, in_w, out_w, w1, w2, SRCb, WIb, WOb, W1b, W2b);

    // 1. fused Q-proj + KV-proj + cached K/V scatter (one launch)
    qkv_scatter<<<dim3(1152 + NKBLK + (SC / 64) * H), blk, 0, stream>>>(
        SRCb, WIb, in_b, Qb, KF, VT, rec_idx, k_cached, v_cached, cac_idx);
    // 2. attention (QBLK=128, split-K=4) + combine
    attn_mfma<<<dim3(B * H * (S / 128), NKH), blk, 0, stream>>>(
        Qb, KF, VT, Opart, ML);
    attn_combine<<<dim3((B * H * S * HD / 4) / 256), blk, 0, stream>>>(
        Opart, ML, CTXb);
    // 3. out projection -> bf16 AO
    gemm64<0, 0, 1><<<dim3(D / 64, (B * S) / 64), blk, 0, stream>>>(
        CTXb, WOb, out_b, AOb, nullptr, B * S, D, D, nullptr);
    // 4. LN1: Xb = LN(src + AOb)  (bf16 out only)
    ln_kernel<1, 0><<<dim3(B * S), blk, 0, stream>>>(
        src, AOb, n1w, n1b, Xb);
    // 5. FFN1 + ReLU -> bf16 hidden
    gemm128<0, 1, 1><<<dim3(DFF / 128, (B * S) / 128), blk, 0, stream>>>(
        Xb, W1b, b1, HIDb, nullptr, B * S, DFF, D, nullptr);
    // 6. FFN2 -> bf16 AO (reuse AOb; LN1 already consumed it)
    gemm64<0, 0, 1><<<dim3(D / 64, (B * S) / 64), blk, 0, stream>>>(
        HIDb, W2b, b2, AOb, nullptr, B * S, D, DFF, nullptr);
    // 7. LN2 -> d_out (fp32)
    ln_kernel<0, 1><<<dim3(B * S), blk, 0, stream>>>(
        Xb, AOb, n2w, n2b, out);
}

// Round 18
// 203.030 us; speedup vs baseline: 1.0906x; 1.0047x over previous
//
#include <hip/hip_runtime.h>
#include <hip/hip_bf16.h>
#include <cstdint>
#include <math.h>

#define B 2
#define S 3072
#define D 512
#define H 8
#define HD 64
#define DFF 2048
#define R 768
#define SC (S - R)
#define EPS 1e-5f
#define QSCALE 0.1803368801111137f   // log2(e)/sqrt(64) folded into Q
#define NKH 4                        // split-K factor

typedef __attribute__((ext_vector_type(8))) short s8v;   // 8 x bf16 (4 VGPR)
typedef __attribute__((ext_vector_type(4))) short s4v;   // 4 x bf16 (2 VGPR)
typedef __attribute__((ext_vector_type(4))) float f4v;   // mfma accumulator

__device__ inline short f2bf(float x) {
    __hip_bfloat16 h = __float2bfloat16(x);
    return __builtin_bit_cast(short, h);
}
__device__ inline float bf2f(short s) {
    unsigned int u = (unsigned int)(unsigned short)s << 16;
    return __builtin_bit_cast(float, u);
}
__device__ inline unsigned int pack2bf(float a, float b) {
    return (unsigned int)(unsigned short)f2bf(a) |
           ((unsigned int)(unsigned short)f2bf(b) << 16);
}

// K=16 bf16 MFMA (PV sub-tiles): builtin if present, else raw asm.
__device__ __forceinline__ f4v mfma16(s4v a, s4v b, f4v c) {
#if __has_builtin(__builtin_amdgcn_mfma_f32_16x16x16bf16_1k)
    return __builtin_amdgcn_mfma_f32_16x16x16bf16_1k(a, b, c, 0, 0, 0);
#else
    asm("v_mfma_f32_16x16x16_bf16 %0, %1, %2, %0" : "+v"(c) : "v"(a), "v"(b));
    return c;
#endif
}

// global -> LDS direct 16B load
__device__ __forceinline__ void gload16(const short* g, short* l) {
    auto l3 = reinterpret_cast<__attribute__((address_space(3))) short*>(
        reinterpret_cast<uintptr_t>(l));
    auto g1 = reinterpret_cast<const __attribute__((address_space(1))) short*>(
        reinterpret_cast<uintptr_t>(g));
    __builtin_amdgcn_global_load_lds(g1, l3, 16, 0, 0);
}

// ---------------------------------------------------------------------------
// Fused fp32 -> bf16 conversion: src + all 4 weight matrices, one launch.
// ---------------------------------------------------------------------------
__global__ __launch_bounds__(256) void cvt_all(
    const float* __restrict__ src, const float* __restrict__ w_in,
    const float* __restrict__ w_out, const float* __restrict__ w_1,
    const float* __restrict__ w_2,
    short* __restrict__ o_src, short* __restrict__ o_in,
    short* __restrict__ o_out, short* __restrict__ o_1,
    short* __restrict__ o_2)
{
    int i = (blockIdx.x * 256 + threadIdx.x) * 4;
    const int nS = B * S * D;
    const int n0 = nS + 3 * D * D, n1 = n0 + D * D, n2 = n1 + DFF * D;
    const int n3 = n2 + D * DFF;
    if (i >= n3) return;
    const float* sp; short* dp; int off;
    if (i < nS)      { sp = src;   dp = o_src; off = i; }
    else if (i < n0) { sp = w_in;  dp = o_in;  off = i - nS; }
    else if (i < n1) { sp = w_out; dp = o_out; off = i - n0; }
    else if (i < n2) { sp = w_1;   dp = o_1;   off = i - n1; }
    else             { sp = w_2;   dp = o_2;   off = i - n2; }
    float4 v = *(const float4*)(sp + off);
    short4 o = { f2bf(v.x), f2bf(v.y), f2bf(v.z), f2bf(v.w) };
    *(short4*)(dp + off) = o;
}

// ---------------------------------------------------------------------------
// 128x128 bf16 MFMA GEMM (m97 structure) — verified.  Used for FFN1 only.
// ---------------------------------------------------------------------------
template<int MODE, int RELU, int OUTBF>
__global__ __launch_bounds__(256) void gemm128(
    const short* __restrict__ A, const short* __restrict__ W,
    const float* __restrict__ bias, void* __restrict__ C0v,
    void* __restrict__ C1v, int M, int N, int K,
    const int* __restrict__ gather_idx)
{
    __shared__ short Al[128 * 32];
    __shared__ short Bl[128 * 32];
    const int t = threadIdx.x;
    const int bm = blockIdx.y * 128, bn = blockIdx.x * 128;
    const int lane = t & 63, w = t >> 6;
    const int wm = (w >> 1) * 64, wn = (w & 1) * 64;
    const int lr = lane & 15, lk = lane >> 4;

    const int q1 = t, q2 = t + 256;
    const int r1 = q1 >> 2, c1 = (q1 & 3) ^ (r1 & 3);
    const int r2 = q2 >> 2, c2 = (q2 & 3) ^ (r2 & 3);
    long ga1 = (long)(bm + r1) * K + c1 * 8;
    long ga2 = (long)(bm + r2) * K + c2 * 8;
    const long gb1 = (long)(bn + r1) * K + c1 * 8;
    const long gb2 = (long)(bn + r2) * K + c2 * 8;

    f4v acc[4][4] = {};

    for (int k0 = 0; k0 < K; k0 += 32) {
        __syncthreads();
        gload16(A + ga1 + k0, Al + q1 * 8);
        gload16(A + ga2 + k0, Al + q2 * 8);
        gload16(W + gb1 + k0, Bl + q1 * 8);
        gload16(W + gb2 + k0, Bl + q2 * 8);
        __syncthreads();

        s8v af[4], bf[4];
#pragma unroll
        for (int mi = 0; mi < 4; mi++) {
            int ra = wm + mi * 16 + lr;
            af[mi] = *(const s8v*)&Al[ra * 32 + ((lk ^ (ra & 3)) * 8)];
        }
#pragma unroll
        for (int ni = 0; ni < 4; ni++) {
            int rb = wn + ni * 16 + lr;
            bf[ni] = *(const s8v*)&Bl[rb * 32 + ((lk ^ (rb & 3)) * 8)];
        }
#pragma unroll
        for (int mi = 0; mi < 4; mi++)
#pragma unroll
            for (int ni = 0; ni < 4; ni++)
                acc[mi][ni] = __builtin_amdgcn_mfma_f32_16x16x32_bf16(
                    af[mi], bf[ni], acc[mi][ni], 0, 0, 0);
    }

#pragma unroll
    for (int mi = 0; mi < 4; mi++) {
#pragma unroll
        for (int ni = 0; ni < 4; ni++) {
#pragma unroll
            for (int i = 0; i < 4; i++) {
                int m = bm + wm + mi * 16 + lk * 4 + i;
                int n = bn + wn + ni * 16 + lr;
                float v = acc[mi][ni][i] + bias[n];
                if (RELU) v = fmaxf(v, 0.f);
                if (OUTBF) ((short*)C0v)[(long)m * N + n] = f2bf(v);
                else       ((float*)C0v)[(long)m * N + n] = v;
            }
        }
    }
}

// ---------------------------------------------------------------------------
// 64x64 bf16 MFMA GEMM body (BK=64), verified R13/R14.  Called by wrappers.
// ---------------------------------------------------------------------------
template<int MODE, int RELU, int OUTBF>
__device__ __forceinline__ void gemm64_body(
    const short* __restrict__ A, const short* __restrict__ W,
    const float* __restrict__ bias, void* __restrict__ C0v,
    void* __restrict__ C1v, int M, int N, int K,
    const int* __restrict__ gather_idx, int bm, int bn,
    short* Al, short* Bl)
{
    const int t = threadIdx.x;
    const int lane = t & 63, w = t >> 6;
    const int wm = (w >> 1) * 32, wn = (w & 1) * 32;
    const int lr = lane & 15, lk = lane >> 4;

    const int cq1 = t, cq2 = t + 256;
    const int r1 = cq1 >> 3, s1 = (cq1 & 7) ^ (r1 & 7);
    const int r2 = cq2 >> 3, s2 = (cq2 & 7) ^ (r2 & 7);
    long ga1, ga2;
    if (MODE == 2) {
        int m1 = bm + r1; int b1 = m1 >= R; int i1 = m1 - b1 * R;
        ga1 = ((long)b1 * S + gather_idx[i1]) * K + s1 * 8;
        int m2 = bm + r2; int b2 = m2 >= R; int i2 = m2 - b2 * R;
        ga2 = ((long)b2 * S + gather_idx[i2]) * K + s2 * 8;
    } else {
        ga1 = (long)(bm + r1) * K + s1 * 8;
        ga2 = (long)(bm + r2) * K + s2 * 8;
    }
    const long gb1 = (long)(bn + r1) * K + s1 * 8;
    const long gb2 = (long)(bn + r2) * K + s2 * 8;

    f4v acc[2][2] = {};

    for (int k0 = 0; k0 < K; k0 += 64) {
        __syncthreads();
        gload16(A + ga1 + k0, Al + cq1 * 8);
        gload16(A + ga2 + k0, Al + cq2 * 8);
        gload16(W + gb1 + k0, Bl + cq1 * 8);
        gload16(W + gb2 + k0, Bl + cq2 * 8);
        __syncthreads();

#pragma unroll
        for (int ks = 0; ks < 2; ks++) {
            s8v af[2], bf[2];
#pragma unroll
            for (int mi = 0; mi < 2; mi++) {
                int ra = wm + mi * 16 + lr;
                af[mi] = *(const s8v*)&Al[ra * 64 + (((ks * 4 + lk) ^ (ra & 7)) * 8)];
            }
#pragma unroll
            for (int ni = 0; ni < 2; ni++) {
                int rb = wn + ni * 16 + lr;
                bf[ni] = *(const s8v*)&Bl[rb * 64 + (((ks * 4 + lk) ^ (rb & 7)) * 8)];
            }
#pragma unroll
            for (int mi = 0; mi < 2; mi++)
#pragma unroll
                for (int ni = 0; ni < 2; ni++)
                    acc[mi][ni] = __builtin_amdgcn_mfma_f32_16x16x32_bf16(
                        af[mi], bf[ni], acc[mi][ni], 0, 0, 0);
        }
    }

#pragma unroll
    for (int mi = 0; mi < 2; mi++) {
#pragma unroll
        for (int ni = 0; ni < 2; ni++) {
#pragma unroll
            for (int i = 0; i < 4; i++) {
                int m = bm + wm + mi * 16 + lk * 4 + i;
                int n = bn + wn + ni * 16 + lr;
                float v = acc[mi][ni][i] + bias[n];
                if (RELU) v = fmaxf(v, 0.f);
                if (MODE == 0) {
                    if (OUTBF) ((short*)C0v)[(long)m * N + n] = f2bf(v);
                    else       ((float*)C0v)[(long)m * N + n] = v;
                } else if (MODE == 1) {     // Q scatter (pre-scaled) -> bf16
                    int b = m >= S; int s = m - b * S;
                    int h = n >> 6, hd = n & 63;
                    ((short*)C0v)[(((long)(b * H + h)) * S + s) * HD + hd] =
                        f2bf(v * QSCALE);
                } else {                    // K row-major / V transposed
                    int b = m >= R; int i2 = m - b * R;
                    int s = gather_idx[i2];
                    int c = n;
                    if (c < D) {
                        int h = c >> 6, hd = c & 63;
                        ((short*)C0v)[(((long)(b * H + h)) * S + s) * HD + hd] = f2bf(v);
                    } else {
                        c -= D;
                        int h = c >> 6, hd = c & 63;
                        ((short*)C1v)[(((long)(b * H + h)) * HD + hd) * S + s] = f2bf(v);
                    }
                }
            }
        }
    }
}

// plain gemm64 wrapper (out-proj, FFN2)
template<int MODE, int RELU, int OUTBF>
__global__ __launch_bounds__(256) void gemm64(
    const short* __restrict__ A, const short* __restrict__ W,
    const float* __restrict__ bias, void* __restrict__ C0v,
    void* __restrict__ C1v, int M, int N, int K,
    const int* __restrict__ gather_idx)
{
    __shared__ short Al[64 * 64];
    __shared__ short Bl[64 * 64];
    gemm64_body<MODE, RELU, OUTBF>(A, W, bias, C0v, C1v, M, N, K, gather_idx,
                                   blockIdx.y * 64, blockIdx.x * 64, Al, Bl);
}

// ---------------------------------------------------------------------------
// Fused Q-proj + KV-proj + cached K/V scatter, one launch.
// ---------------------------------------------------------------------------
#define NKBLK ((H * SC * HD) / 256)             // 4608
__global__ __launch_bounds__(256) void qkv_scatter(
    const short* __restrict__ SRCb, const short* __restrict__ WIb,
    const float* __restrict__ in_b, short* __restrict__ Qb,
    short* __restrict__ KF, short* __restrict__ VT,
    const int* __restrict__ rec_idx,
    const float* __restrict__ kc, const float* __restrict__ vc,
    const int* __restrict__ cidx)
{
    __shared__ short Al[64 * 64];
    __shared__ short Bl[64 * 64];
    int g = blockIdx.x;
    if (g < 768) {                              // Q tiles
        int bn = (g & 7) * 64, bm = (g >> 3) * 64;
        gemm64_body<1, 0, 0>(SRCb, WIb, in_b, Qb, nullptr,
                             B * S, D, D, rec_idx, bm, bn, Al, Bl);
    } else if (g < 1152) {                      // KV tiles
        int gg = g - 768;
        int bn = (gg & 15) * 64, bm = (gg >> 4) * 64;
        gemm64_body<2, 0, 0>(SRCb, WIb + D * D, in_b + D, KF, VT,
                             B * R, 2 * D, D, rec_idx, bm, bn, Al, Bl);
    } else if (g < 1152 + NKBLK) {              // cached-K scatter
        long e = (long)(g - 1152) * 256 + threadIdx.x;
        int hd = e & 63;
        long tmp = e >> 6;
        int j = (int)(tmp % SC);
        int h = (int)(tmp / SC);
        int s = cidx[j];
        short v = f2bf(kc[e]);
        KF[(((long)(0 * H + h)) * S + s) * HD + hd] = v;
        KF[(((long)(1 * H + h)) * S + s) * HD + hd] = v;
    } else {                                    // cached-V^T scatter
        int bb = g - 1152 - NKBLK;              // 0..287
        const int h = bb / (SC / 64);
        const int jblk = bb % (SC / 64);
        const int hd = threadIdx.x & 63, jg = threadIdx.x >> 6;
        const int j0 = jblk * 64 + jg * 16;
#pragma unroll 4
        for (int jj = 0; jj < 16; jj++) {
            int j = j0 + jj;
            int s = cidx[j];
            short v = f2bf(vc[((long)h * SC + j) * HD + hd]);
            VT[(((long)(0 * H + h)) * HD + hd) * S + s] = v;
            VT[(((long)(1 * H + h)) * HD + hd) * S + s] = v;
        }
    }
}

// ---------------------------------------------------------------------------
// MFMA flash attention v6: v5 (QBLK=128, split-K=4) + double-buffered LDS:
// issue next tile's global_load_lds BEFORE computing current tile, ONE
// barrier per K-tile (was 2).  Load latency overlaps QK/softmax/PV.
// Hazard: buf[nxt] writes at iter t follow the iter t-1 barrier that
// retired all reads of its old contents; buf[cur] reads precede this
// wave's own barrier.
// ---------------------------------------------------------------------------
__global__ __launch_bounds__(256) void attn_mfma(
    const short* __restrict__ Qb, const short* __restrict__ KF,
    const short* __restrict__ VT, short* __restrict__ Opart,
    float* __restrict__ ML)
{
    __shared__ short Ks[2][64 * 64];
    __shared__ short Vt[2][64 * 64];
    const int t = threadIdx.x;
    const int lane = t & 63, w = t >> 6;
    const int lr = lane & 15, lk = lane >> 4;
    const int nq = S / 128;
    const int qt = blockIdx.x % nq;
    const int bh = blockIdx.x / nq;
    const int kh = blockIdx.y;
    const long base = (long)bh * S;

    const int qrA = qt * 128 + w * 16 + lr;
    const int qrB = qrA + 64;
    const s8v qfA0 = *(const s8v*)&Qb[(base + qrA) * HD + lk * 8];
    const s8v qfA1 = *(const s8v*)&Qb[(base + qrA) * HD + 32 + lk * 8];
    const s8v qfB0 = *(const s8v*)&Qb[(base + qrB) * HD + lk * 8];
    const s8v qfB1 = *(const s8v*)&Qb[(base + qrB) * HD + 32 + lk * 8];

    const int cq1 = t, cq2 = t + 256;
    const int sr1 = cq1 >> 3, sc1 = (cq1 & 7) ^ (sr1 & 7);
    const int sr2 = cq2 >> 3, sc2 = (cq2 & 7) ^ (sr2 & 7);
    const long kb1 = (base + sr1) * HD + sc1 * 8;
    const long kb2 = (base + sr2) * HD + sc2 * 8;
    const long vb1 = ((long)bh * HD + sr1) * S + sc1 * 8;
    const long vb2 = ((long)bh * HD + sr2) * S + sc2 * 8;

    f4v odA[4] = {}, odB[4] = {};
    f4v lsA = {}, lsB = {};
    const s4v ones = { 0x3F80, 0x3F80, 0x3F80, 0x3F80 };  // bf16 1.0 x4

    const int kbeg = kh * (S / NKH), kend = kbeg + S / NKH;

    // prologue: stage first tile into buf 0
    gload16(KF + kb1 + (long)kbeg * HD, Ks[0] + cq1 * 8);
    gload16(KF + kb2 + (long)kbeg * HD, Ks[0] + cq2 * 8);
    gload16(VT + vb1 + kbeg, Vt[0] + cq1 * 8);
    gload16(VT + vb2 + kbeg, Vt[0] + cq2 * 8);
    __syncthreads();

    int cur = 0;
    for (int k0 = kbeg; k0 < kend; k0 += 64) {
        const int nxt = cur ^ 1;
        if (k0 + 64 < kend) {                    // issue next tile early
            gload16(KF + kb1 + (long)(k0 + 64) * HD, Ks[nxt] + cq1 * 8);
            gload16(KF + kb2 + (long)(k0 + 64) * HD, Ks[nxt] + cq2 * 8);
            gload16(VT + vb1 + (k0 + 64), Vt[nxt] + cq1 * 8);
            gload16(VT + vb2 + (k0 + 64), Vt[nxt] + cq2 * 8);
        }
        const short* Kc = Ks[cur];
        const short* Vc = Vt[cur];

        f4v scA[4], scB[4];
#pragma unroll
        for (int st = 0; st < 4; st++) {
            const int row = st * 16 + lr;
            s8v kf0 = *(const s8v*)&Kc[row * 64 + ((lk ^ (lr & 7)) * 8)];
            s8v kf1 = *(const s8v*)&Kc[row * 64 + (((4 + lk) ^ (lr & 7)) * 8)];
            f4v a = {};
            a = __builtin_amdgcn_mfma_f32_16x16x32_bf16(kf0, qfA0, a, 0, 0, 0);
            a = __builtin_amdgcn_mfma_f32_16x16x32_bf16(kf1, qfA1, a, 0, 0, 0);
            scA[st] = a;
            f4v b = {};
            b = __builtin_amdgcn_mfma_f32_16x16x32_bf16(kf0, qfB0, b, 0, 0, 0);
            b = __builtin_amdgcn_mfma_f32_16x16x32_bf16(kf1, qfB1, b, 0, 0, 0);
            scB[st] = b;
        }

        s4v paA[4], paB[4];
#pragma unroll
        for (int st = 0; st < 4; st++) {
            float a0 = exp2f(scA[st][0]), a1 = exp2f(scA[st][1]);
            float a2 = exp2f(scA[st][2]), a3 = exp2f(scA[st][3]);
            int2 pwa = { (int)pack2bf(a0, a1), (int)pack2bf(a2, a3) };
            paA[st] = __builtin_bit_cast(s4v, pwa);
            lsA = mfma16(paA[st], ones, lsA);
            float b0 = exp2f(scB[st][0]), b1 = exp2f(scB[st][1]);
            float b2 = exp2f(scB[st][2]), b3 = exp2f(scB[st][3]);
            int2 pwb = { (int)pack2bf(b0, b1), (int)pack2bf(b2, b3) };
            paB[st] = __builtin_bit_cast(s4v, pwb);
            lsB = mfma16(paB[st], ones, lsB);
        }

#pragma unroll
        for (int dst = 0; dst < 4; dst++) {
            const int d = dst * 16 + lr;
#pragma unroll
            for (int st = 0; st < 4; st++) {
                int cc = 2 * st + (lk >> 1);
                s4v vf = *(const s4v*)&Vc[d * 64 + ((cc ^ (lr & 7)) * 8) + (lk & 1) * 4];
                odA[dst] = mfma16(paA[st], vf, odA[dst]);
                odB[dst] = mfma16(paB[st], vf, odB[dst]);
            }
        }

        __syncthreads();                         // single barrier per tile
        cur = nxt;
    }

    const long pb = ((long)(kh * 16 + bh)) * S;
    if (lr == 0) {
#pragma unroll
        for (int i = 0; i < 4; i++) {
            int q = qt * 128 + w * 16 + lk * 4 + i;
            ML[pb + q] = lsA[i];
            ML[pb + q + 64] = lsB[i];
        }
    }
#pragma unroll
    for (int dst = 0; dst < 4; dst++)
#pragma unroll
        for (int i = 0; i < 4; i++) {
            int q = qt * 128 + w * 16 + lk * 4 + i;
            int d = dst * 16 + lr;
            Opart[(pb + q) * HD + d] = f2bf(odA[dst][i]);
            Opart[(pb + q + 64) * HD + d] = f2bf(odB[dst][i]);
        }
}

// ---------------------------------------------------------------------------
// Combine NKH key-slice bf16 partials: O = sum O_i / sum l_i -> bf16 ctx.
// ---------------------------------------------------------------------------
__global__ __launch_bounds__(256) void attn_combine(
    const short* __restrict__ Opart, const float* __restrict__ ML,
    short* __restrict__ ctxb)
{
    long idx = (long)blockIdx.x * 256 + threadIdx.x;
    long f = idx * 4;
    int d = (int)(f & 63);
    long x = f >> 6;
    int bh = (int)(x / S);
    int q = (int)(x - (long)bh * S);
    float l = 0.f;
    float4 o = {0.f, 0.f, 0.f, 0.f};
#pragma unroll
    for (int kh = 0; kh < NKH; kh++) {
        long xx = x + (long)kh * 16 * S;
        l += ML[xx];
        short4 p = *(const short4*)&Opart[xx * HD + d];
        o.x += bf2f(p.x); o.y += bf2f(p.y);
        o.z += bf2f(p.z); o.w += bf2f(p.w);
    }
    float inv = 1.f / l;
    int b = bh >> 3, h = bh & 7;
    short4 r;
    r.x = f2bf(o.x * inv);
    r.y = f2bf(o.y * inv);
    r.z = f2bf(o.z * inv);
    r.w = f2bf(o.w * inv);
    *(short4*)&ctxb[((long)(b * S + q)) * D + h * HD + d] = r;
}

// ---------------------------------------------------------------------------
// LayerNorm: out = LN(a + r) * g + be.  a: fp32 (AF32=1) or bf16; r: bf16.
// out: fp32 (OUTF32=1) or bf16.
// ---------------------------------------------------------------------------
template<int AF32, int OUTF32>
__global__ __launch_bounds__(256) void ln_kernel(
    const void* __restrict__ av, const short* __restrict__ rv,
    const float* __restrict__ g, const float* __restrict__ be,
    void* __restrict__ outv)
{
    const long row = blockIdx.x;
    const int t = threadIdx.x;
    float a0, a1;
    if (AF32) {
        const float* pa = (const float*)av + row * D;
        a0 = pa[t]; a1 = pa[t + 256];
    } else {
        const short* pa = (const short*)av + row * D;
        a0 = bf2f(pa[t]); a1 = bf2f(pa[t + 256]);
    }
    const short* pr = rv + row * D;
    float v0 = a0 + bf2f(pr[t]);
    float v1 = a1 + bf2f(pr[t + 256]);
    float s1 = v0 + v1, s2 = v0 * v0 + v1 * v1;
    for (int off = 32; off; off >>= 1) {
        s1 += __shfl_xor(s1, off, 64);
        s2 += __shfl_xor(s2, off, 64);
    }
    __shared__ float red[8];
    int w = t >> 6, lane = t & 63;
    if (lane == 0) { red[w] = s1; red[4 + w] = s2; }
    __syncthreads();
    float sum = red[0] + red[1] + red[2] + red[3];
    float ssq = red[4] + red[5] + red[6] + red[7];
    float mean = sum * (1.f / D);
    float var = ssq * (1.f / D) - mean * mean;
    float rstd = rsqrtf(var + EPS);
    float r0 = (v0 - mean) * rstd * g[t] + be[t];
    float r1 = (v1 - mean) * rstd * g[t + 256] + be[t + 256];
    if (OUTF32) {
        float* o = (float*)outv + row * D;
        o[t] = r0; o[t + 256] = r1;
    } else {
        short* o = (short*)outv + row * D;
        o[t] = f2bf(r0); o[t + 256] = f2bf(r1);
    }
}

// ---------------------------------------------------------------------------
extern "C" void kernel_launch(void* const* d_in, const int* in_sizes, int n_in,
                              void* d_out, int out_size, void* d_ws, size_t ws_size,
                              hipStream_t stream)
{
    const float* src      = (const float*)d_in[0];
    const int*   rec_idx  = (const int*)d_in[1];
    const int*   cac_idx  = (const int*)d_in[2];
    const float* k_cached = (const float*)d_in[3];
    const float* v_cached = (const float*)d_in[4];
    const float* in_w     = (const float*)d_in[5];
    const float* in_b     = (const float*)d_in[6];
    const float* out_w    = (const float*)d_in[7];
    const float* out_b    = (const float*)d_in[8];
    const float* w1       = (const float*)d_in[9];
    const float* b1       = (const float*)d_in[10];
    const float* w2       = (const float*)d_in[11];
    const float* b2       = (const float*)d_in[12];
    const float* n1w      = (const float*)d_in[13];
    const float* n1b      = (const float*)d_in[14];
    const float* n2w      = (const float*)d_in[15];
    const float* n2b      = (const float*)d_in[16];

    short* SRCb = (short*)d_ws;              // 3145728
    short* WIb  = SRCb + 3145728;            // 786432
    short* WOb  = WIb  + 786432;             // 262144
    short* W1b  = WOb  + 262144;             // 1048576
    short* W2b  = W1b  + 1048576;            // 1048576
    short* Qb   = W2b  + 1048576;            // 3145728
    short* KF   = Qb   + 3145728;            // 3145728
    short* VT   = KF   + 3145728;            // 3145728 (V^T [b,h,hd,s])
    short* CTXb = VT   + 3145728;            // 3145728
    short* Xb   = CTXb + 3145728;            // 3145728
    short* AOb  = Xb   + 3145728;            // 3145728 (bf16 residual branch)
    short* HIDb = AOb  + 3145728;            // 12582912 (FFN hidden bf16)
    short* Opart = HIDb;                     // alias: 12582912 sh = NKH*16*S*HD
    float* ML   = (float*)(HIDb + 12582912); // 196608 f (NKH*16*S l-values)
    float* out  = (float*)d_out;

    dim3 blk(256);

    // 0. fused fp32->bf16 conversions (src + 4 weights), one launch
    cvt_all<<<dim3((B * S * D + 3 * D * D + D * D + 2 * DFF * D) / 1024),
              blk, 0, stream>>>(
        src, in_w, out_w, w1, w2, SRCb, WIb, WOb, W1b, W2b);

    // 1. fused Q-proj + KV-proj + cached K/V scatter (one launch)
    qkv_scatter<<<dim3(1152 + NKBLK + (SC / 64) * H), blk, 0, stream>>>(
        SRCb, WIb, in_b, Qb, KF, VT, rec_idx, k_cached, v_cached, cac_idx);
    // 2. attention (QBLK=128, split-K=4, double-buffered) + combine
    attn_mfma<<<dim3(B * H * (S / 128), NKH), blk, 0, stream>>>(
        Qb, KF, VT, Opart, ML);
    attn_combine<<<dim3((B * H * S * HD / 4) / 256), blk, 0, stream>>>(
        Opart, ML, CTXb);
    // 3. out projection -> bf16 AO
    gemm64<0, 0, 1><<<dim3(D / 64, (B * S) / 64), blk, 0, stream>>>(
        CTXb, WOb, out_b, AOb, nullptr, B * S, D, D, nullptr);
    // 4. LN1: Xb = LN(src + AOb)  (bf16 out only)
    ln_kernel<1, 0><<<dim3(B * S), blk, 0, stream>>>(
        src, AOb, n1w, n1b, Xb);
    // 5. FFN1 + ReLU -> bf16 hidden
    gemm128<0, 1, 1><<<dim3(DFF / 128, (B * S) / 128), blk, 0, stream>>>(
        Xb, W1b, b1, HIDb, nullptr, B * S, DFF, D, nullptr);
    // 6. FFN2 -> bf16 AO (reuse AOb; LN1 already consumed it)
    gemm64<0, 0, 1><<<dim3(D / 64, (B * S) / 64), blk, 0, stream>>>(
        HIDb, W2b, b2, AOb, nullptr, B * S, D, DFF, nullptr);
    // 7. LN2 -> d_out (fp32)
    ln_kernel<0, 1><<<dim3(B * S), blk, 0, stream>>>(
        Xb, AOb, n2w, n2b, out);
}